// Round 2
// baseline (920.154 us; speedup 1.0000x reference)
//
#include <hip/hip_runtime.h>
#include <hip/hip_bf16.h>
#include <cmath>

typedef __bf16 bf16x8 __attribute__((ext_vector_type(8)));
typedef float f32x4 __attribute__((ext_vector_type(4)));
typedef unsigned short u16;
typedef unsigned int u32;

#define DEV __device__ __forceinline__

static constexpr int BB = 2;
static constexpr int T = 2048;
static constexpr int DM = 2048;
static constexpr int NH = 16;
static constexpr int HD = 128;
static constexpr int FF = 8192;
static constexpr int M = BB * T;      // 4096
static constexpr int NQKV = 3 * DM;   // 6144

DEV u16 f2b(float f) {
  u32 u = __builtin_bit_cast(u32, f);
  u = (u + 0x7FFFu + ((u >> 16) & 1u)) >> 16;
  return (u16)u;
}
DEV float b2f(u16 h) {
  u32 u = ((u32)h) << 16;
  return __builtin_bit_cast(float, u);
}

// ---------------- conversions ----------------

__global__ void cvt_f32_to_bf16(const float* __restrict__ in, u16* __restrict__ out, int n4) {
  int i = blockIdx.x * blockDim.x + threadIdx.x;
  if (i >= n4) return;
  float4 v = reinterpret_cast<const float4*>(in)[i];
  ushort4 o;
  o.x = f2b(v.x); o.y = f2b(v.y); o.z = f2b(v.z); o.w = f2b(v.w);
  reinterpret_cast<ushort4*>(out)[i] = o;
}

// W [K][N] f32  ->  Wt [N][K] bf16
__global__ void transpose_cvt(const float* __restrict__ W, u16* __restrict__ Wt, int K, int N) {
  __shared__ float tile[32][33];
  int nb = blockIdx.x * 32, kb = blockIdx.y * 32;
  int tx = threadIdx.x & 31, ty = threadIdx.x >> 5;  // ty 0..7
#pragma unroll
  for (int r = 0; r < 32; r += 8)
    tile[ty + r][tx] = W[(size_t)(kb + ty + r) * N + nb + tx];
  __syncthreads();
#pragma unroll
  for (int r = 0; r < 32; r += 8)
    Wt[(size_t)(nb + ty + r) * K + kb + tx] = f2b(tile[tx][ty + r]);
}

// ---------------- GEMM ----------------
// C[M][N] = A[M][K] * Bt[N][K]^T, bf16 inputs, f32 accum.
// EPI 0: scatter qkv -> q/k/v (B,H,T,hd) bf16
// EPI 1: plain bf16 out
// EPI 2: bias + exact GELU, bf16 out
// EPI 3: bias + resid_f32 + resid_bf, f32 out
template <int EPI>
__global__ __launch_bounds__(256) void gemm_bf16(
    const u16* __restrict__ A, const u16* __restrict__ Bt, int Ndim, int K,
    u16* __restrict__ out_bf, float* __restrict__ out_f32,
    const float* __restrict__ bias,
    const float* __restrict__ resid_f32, const u16* __restrict__ resid_bf) {
  __shared__ __align__(16) u16 lA[128 * 40];
  __shared__ __align__(16) u16 lB[128 * 40];
  const int t = threadIdx.x;
  const int m0 = blockIdx.y * 128, n0 = blockIdx.x * 128;
  const int wave = t >> 6, lane = t & 63;
  const int wm = wave >> 1, wn = wave & 1;
  const int lr = lane & 15, lk = lane >> 4;
  const int r0 = t >> 2, kc = (t & 3) * 8;  // staging rows r0, r0+64

  f32x4 acc[4][4] = {};

  for (int kt = 0; kt < K; kt += 32) {
    int4 a0 = *reinterpret_cast<const int4*>(&A[(size_t)(m0 + r0) * K + kt + kc]);
    int4 a1 = *reinterpret_cast<const int4*>(&A[(size_t)(m0 + r0 + 64) * K + kt + kc]);
    int4 b0 = *reinterpret_cast<const int4*>(&Bt[(size_t)(n0 + r0) * K + kt + kc]);
    int4 b1 = *reinterpret_cast<const int4*>(&Bt[(size_t)(n0 + r0 + 64) * K + kt + kc]);
    __syncthreads();  // protect LDS from previous iteration's readers
    *reinterpret_cast<int4*>(&lA[r0 * 40 + kc]) = a0;
    *reinterpret_cast<int4*>(&lA[(r0 + 64) * 40 + kc]) = a1;
    *reinterpret_cast<int4*>(&lB[r0 * 40 + kc]) = b0;
    *reinterpret_cast<int4*>(&lB[(r0 + 64) * 40 + kc]) = b1;
    __syncthreads();
    bf16x8 af[4], bfr[4];
#pragma unroll
    for (int i = 0; i < 4; ++i) {
      af[i]  = *reinterpret_cast<const bf16x8*>(&lA[(wm * 64 + i * 16 + lr) * 40 + lk * 8]);
      bfr[i] = *reinterpret_cast<const bf16x8*>(&lB[(wn * 64 + i * 16 + lr) * 40 + lk * 8]);
    }
#pragma unroll
    for (int i = 0; i < 4; ++i)
#pragma unroll
      for (int j = 0; j < 4; ++j)
        acc[i][j] = __builtin_amdgcn_mfma_f32_16x16x32_bf16(af[i], bfr[j], acc[i][j], 0, 0, 0);
  }

#pragma unroll
  for (int i = 0; i < 4; ++i) {
#pragma unroll
    for (int j = 0; j < 4; ++j) {
#pragma unroll
      for (int r = 0; r < 4; ++r) {
        int gr = m0 + wm * 64 + i * 16 + (lane >> 4) * 4 + r;
        int gc = n0 + wn * 64 + j * 16 + (lane & 15);
        float v = acc[i][j][r];
        if constexpr (EPI == 0) {
          int part = gc >> 11, cc = gc & 2047;
          int head = cc >> 7, d = cc & 127;
          int b = gr >> 11, tt = gr & 2047;
          out_bf[(size_t)part * M * DM + (((size_t)(b * NH + head) * T + tt) * HD + d)] = f2b(v);
        } else if constexpr (EPI == 1) {
          out_bf[(size_t)gr * Ndim + gc] = f2b(v);
        } else if constexpr (EPI == 2) {
          v += bias[gc];
          v = 0.5f * v * (1.0f + erff(v * 0.7071067811865475f));
          out_bf[(size_t)gr * Ndim + gc] = f2b(v);
        } else {
          v += bias[gc] + resid_f32[(size_t)gr * Ndim + gc] + b2f(resid_bf[(size_t)gr * Ndim + gc]);
          out_f32[(size_t)gr * Ndim + gc] = v;
        }
      }
    }
  }
}

// ---------------- attention ----------------
// grid (T/64, B*NH); 4 waves, each owns 16 q-rows; KV tiles of 64; causal flash.
__global__ __launch_bounds__(256) void attn_fwd(
    const u16* __restrict__ qg, const u16* __restrict__ kg,
    const u16* __restrict__ vg, u16* __restrict__ outg) {
  __shared__ __align__(16) u16 lK[64 * 128];   // swizzled rows (256B each)
  __shared__ __align__(16) u16 lV[128 * 72];   // V^T, padded 64->72
  __shared__ __align__(16) u16 lP[4][16 * 72];
  const int t = threadIdx.x;
  const int qi = blockIdx.x, bh = blockIdx.y;
  const int wv = t >> 6, lane = t & 63;
  const int lc = lane & 15, lg = lane >> 4;
  const size_t base = (size_t)bh * T * HD;
  const int q0 = qi * 64;

  bf16x8 qf[4];
#pragma unroll
  for (int kk = 0; kk < 4; ++kk)
    qf[kk] = *reinterpret_cast<const bf16x8*>(
        &qg[base + (size_t)(q0 + wv * 16 + lc) * HD + kk * 32 + lg * 8]);

  f32x4 oacc[8] = {};
  float mrow[4], lrow[4];
#pragma unroll
  for (int r = 0; r < 4; ++r) { mrow[r] = -INFINITY; lrow[r] = 0.f; }

  const float scale = 0.08838834764831845f;  // 1/sqrt(128)
  const int ntiles = qi + 1;
  for (int kt = 0; kt < ntiles; ++kt) {
    __syncthreads();
    // stage K, XOR-swizzled (row-major D=128 would be 32-way conflict)
    // full tile: 64 rows x 256 B = 1024 int4 chunks / 256 threads = 4 iters
#pragma unroll
    for (int h = 0; h < 4; ++h) {
      int c = t + h * 256;
      int row = c >> 4, dcb = (c & 15) * 16;  // byte col 0..240
      int4 val = *reinterpret_cast<const int4*>(
          &kg[base + (size_t)(kt * 64 + row) * HD + (dcb >> 1)]);
      *reinterpret_cast<int4*>(reinterpret_cast<char*>(lK) + row * 256 +
                               (dcb ^ ((row & 7) << 4))) = val;
    }
    // stage V^T (scalar transposed writes)
#pragma unroll
    for (int i = 0; i < 32; ++i) {
      int e = t + i * 256;
      int kvr = e >> 7, d = e & 127;
      lV[d * 72 + kvr] = vg[base + (size_t)(kt * 64 + kvr) * HD + d];
    }
    __syncthreads();

    // S = Q K^T
    f32x4 s[4] = {};
#pragma unroll
    for (int nf = 0; nf < 4; ++nf) {
      int krow = nf * 16 + lc;
#pragma unroll
      for (int kk = 0; kk < 4; ++kk) {
        int dbyte = kk * 64 + lg * 16;
        bf16x8 kf = *reinterpret_cast<const bf16x8*>(
            reinterpret_cast<char*>(lK) + krow * 256 + (dbyte ^ ((krow & 7) << 4)));
        s[nf] = __builtin_amdgcn_mfma_f32_16x16x32_bf16(qf[kk], kf, s[nf], 0, 0, 0);
      }
    }

    // scale + causal mask + row stats
    float rmax[4];
#pragma unroll
    for (int r = 0; r < 4; ++r) rmax[r] = -INFINITY;
#pragma unroll
    for (int nf = 0; nf < 4; ++nf) {
      int col = kt * 64 + nf * 16 + lc;
#pragma unroll
      for (int r = 0; r < 4; ++r) {
        int row = q0 + wv * 16 + lg * 4 + r;
        float sv = s[nf][r] * scale;
        if (col > row) sv = -INFINITY;
        s[nf][r] = sv;
        rmax[r] = fmaxf(rmax[r], sv);
      }
    }
#pragma unroll
    for (int mk = 1; mk < 16; mk <<= 1)
#pragma unroll
      for (int r = 0; r < 4; ++r)
        rmax[r] = fmaxf(rmax[r], __shfl_xor(rmax[r], mk));
    float corr[4];
#pragma unroll
    for (int r = 0; r < 4; ++r) {
      float mnew = fmaxf(mrow[r], rmax[r]);
      corr[r] = expf(mrow[r] - mnew);
      mrow[r] = mnew;
      lrow[r] *= corr[r];
    }
#pragma unroll
    for (int dc = 0; dc < 8; ++dc)
#pragma unroll
      for (int r = 0; r < 4; ++r) oacc[dc][r] *= corr[r];

    // P = exp(s - m) -> lP (per-wave, padded)
#pragma unroll
    for (int nf = 0; nf < 4; ++nf) {
#pragma unroll
      for (int r = 0; r < 4; ++r) {
        float p = expf(s[nf][r] - mrow[r]);
        lrow[r] += p;
        lP[wv][(lg * 4 + r) * 72 + nf * 16 + lc] = f2b(p);
      }
    }
    bf16x8 pa[2];
#pragma unroll
    for (int kk = 0; kk < 2; ++kk)
      pa[kk] = *reinterpret_cast<const bf16x8*>(&lP[wv][lc * 72 + kk * 32 + lg * 8]);
#pragma unroll
    for (int dc = 0; dc < 8; ++dc) {
#pragma unroll
      for (int kk = 0; kk < 2; ++kk) {
        bf16x8 vf = *reinterpret_cast<const bf16x8*>(&lV[(dc * 16 + lc) * 72 + kk * 32 + lg * 8]);
        oacc[dc] = __builtin_amdgcn_mfma_f32_16x16x32_bf16(pa[kk], vf, oacc[dc], 0, 0, 0);
      }
    }
  }

#pragma unroll
  for (int mk = 1; mk < 16; mk <<= 1)
#pragma unroll
    for (int r = 0; r < 4; ++r) lrow[r] += __shfl_xor(lrow[r], mk);

  const int b = bh >> 4, hh = bh & 15;
#pragma unroll
  for (int dc = 0; dc < 8; ++dc)
#pragma unroll
    for (int r = 0; r < 4; ++r) {
      int tt = q0 + wv * 16 + lg * 4 + r;
      int d = dc * 16 + lc;
      float o = oacc[dc][r] / lrow[r];
      outg[(size_t)(b * T + tt) * DM + hh * HD + d] = f2b(o);
    }
}

// ---------------- launch ----------------

extern "C" void kernel_launch(void* const* d_in, const int* in_sizes, int n_in,
                              void* d_out, int out_size, void* d_ws, size_t ws_size,
                              hipStream_t stream) {
  const float* x      = (const float*)d_in[0];
  const float* w_qkv  = (const float*)d_in[1];
  const float* w_proj = (const float*)d_in[2];
  const float* w_ff1  = (const float*)d_in[3];
  const float* b_ff1  = (const float*)d_in[4];
  const float* w_ff2  = (const float*)d_in[5];
  const float* b_ff2  = (const float*)d_in[6];
  float* out = (float*)d_out;

  u16* ws = (u16*)d_ws;
  size_t o = 0;
  u16* x_bf      = ws + o; o += (size_t)M * DM;
  u16* wqkv_t    = ws + o; o += (size_t)NQKV * DM;
  u16* wproj_t   = ws + o; o += (size_t)DM * DM;
  u16* wff1_t    = ws + o; o += (size_t)FF * DM;
  u16* wff2_t    = ws + o; o += (size_t)DM * FF;
  u16* attn_proj = ws + o; o += (size_t)M * DM;
  u16* qbuf      = ws + o;                    // q,k,v,attn_out contiguous
  u16* kbuf      = qbuf + (size_t)M * DM;
  u16* vbuf      = kbuf + (size_t)M * DM;
  u16* attn_out  = vbuf + (size_t)M * DM;
  u16* hbuf      = qbuf;                      // aliases q|k|v|attn_out = M*FF elems

  // conversions
  cvt_f32_to_bf16<<<(M * DM / 4 + 255) / 256, 256, 0, stream>>>(x, x_bf, M * DM / 4);
  transpose_cvt<<<dim3(NQKV / 32, DM / 32), 256, 0, stream>>>(w_qkv, wqkv_t, DM, NQKV);
  transpose_cvt<<<dim3(DM / 32, DM / 32), 256, 0, stream>>>(w_proj, wproj_t, DM, DM);
  transpose_cvt<<<dim3(FF / 32, DM / 32), 256, 0, stream>>>(w_ff1, wff1_t, DM, FF);
  transpose_cvt<<<dim3(DM / 32, FF / 32), 256, 0, stream>>>(w_ff2, wff2_t, FF, DM);

  // qkv projection (scatter into q/k/v)
  gemm_bf16<0><<<dim3(NQKV / 128, M / 128), 256, 0, stream>>>(
      x_bf, wqkv_t, NQKV, DM, qbuf, nullptr, nullptr, nullptr, nullptr);

  // causal flash attention
  attn_fwd<<<dim3(T / 64, BB * NH), 256, 0, stream>>>(qbuf, kbuf, vbuf, attn_out);

  // output projection
  gemm_bf16<1><<<dim3(DM / 128, M / 128), 256, 0, stream>>>(
      attn_out, wproj_t, DM, DM, attn_proj, nullptr, nullptr, nullptr, nullptr);

  // FF1 + GELU (hbuf overwrites q/k/v/attn_out — all consumed by now)
  gemm_bf16<2><<<dim3(FF / 128, M / 128), 256, 0, stream>>>(
      x_bf, wff1_t, FF, DM, hbuf, nullptr, b_ff1, nullptr, nullptr);

  // FF2 + bias + residuals -> f32 out
  gemm_bf16<3><<<dim3(DM / 128, M / 128), 256, 0, stream>>>(
      hbuf, wff2_t, DM, FF, nullptr, out, b_ff2, x, attn_proj);
}

// Round 3
// 864.915 us; speedup vs baseline: 1.0639x; 1.0639x over previous
//
#include <hip/hip_runtime.h>
#include <hip/hip_bf16.h>
#include <cmath>

typedef __bf16 bf16x8 __attribute__((ext_vector_type(8)));
typedef float f32x4 __attribute__((ext_vector_type(4)));
typedef unsigned short u16;
typedef unsigned int u32;

#define DEV __device__ __forceinline__

static constexpr int BB = 2;
static constexpr int T = 2048;
static constexpr int DM = 2048;
static constexpr int NH = 16;
static constexpr int HD = 128;
static constexpr int FF = 8192;
static constexpr int M = BB * T;      // 4096
static constexpr int NQKV = 3 * DM;   // 6144

DEV u16 f2b(float f) {
  u32 u = __builtin_bit_cast(u32, f);
  u = (u + 0x7FFFu + ((u >> 16) & 1u)) >> 16;
  return (u16)u;
}
DEV float b2f(u16 h) {
  u32 u = ((u32)h) << 16;
  return __builtin_bit_cast(float, u);
}

// async global->LDS, 16B per lane; LDS dest = wave-uniform base + lane*16
DEV void gload16(const u16* g, const u16* l) {
  __builtin_amdgcn_global_load_lds(
      (const __attribute__((address_space(1))) void*)(uintptr_t)g,
      (__attribute__((address_space(3))) void*)(unsigned)(uintptr_t)l,
      16, 0, 0);
}

// ---------------- conversions ----------------

__global__ void cvt_f32_to_bf16(const float* __restrict__ in, u16* __restrict__ out, int n4) {
  int i = blockIdx.x * blockDim.x + threadIdx.x;
  if (i >= n4) return;
  float4 v = reinterpret_cast<const float4*>(in)[i];
  ushort4 o;
  o.x = f2b(v.x); o.y = f2b(v.y); o.z = f2b(v.z); o.w = f2b(v.w);
  reinterpret_cast<ushort4*>(out)[i] = o;
}

// W [K][N] f32  ->  Wt [N][K] bf16
__global__ void transpose_cvt(const float* __restrict__ W, u16* __restrict__ Wt, int K, int N) {
  __shared__ float tile[32][33];
  int nb = blockIdx.x * 32, kb = blockIdx.y * 32;
  int tx = threadIdx.x & 31, ty = threadIdx.x >> 5;  // ty 0..7
#pragma unroll
  for (int r = 0; r < 32; r += 8)
    tile[ty + r][tx] = W[(size_t)(kb + ty + r) * N + nb + tx];
  __syncthreads();
#pragma unroll
  for (int r = 0; r < 32; r += 8)
    Wt[(size_t)(nb + ty + r) * K + kb + tx] = f2b(tile[tx][ty + r]);
}

// ---------------- GEMM ----------------
// C[M][N] = A[M][K] * Bt[N][K]^T, bf16 inputs, f32 accum, global_load_lds staging.
// EPI 0: scatter qk -> q/k (B,H,T,hd) bf16
// EPI 1: plain bf16 out
// EPI 2: bias + exact GELU, bf16 out
// EPI 3: bias + resid_f32 + resid_bf, f32 out
// EPI 4: V^T scatter: out[((b*NH+h)*HD+d)*T + t]  (gr = h*128+d, gc = b*2048+t)
template <int EPI>
__global__ __launch_bounds__(256) void gemm_bf16(
    const u16* __restrict__ A, const u16* __restrict__ Bt, int Ndim, int K,
    u16* __restrict__ out_bf, float* __restrict__ out_f32,
    const float* __restrict__ bias,
    const float* __restrict__ resid_f32, const u16* __restrict__ resid_bf) {
  __shared__ __align__(16) u16 lA[128 * 32];
  __shared__ __align__(16) u16 lB[128 * 32];
  const int t = threadIdx.x;
  const int m0 = blockIdx.y * 128, n0 = blockIdx.x * 128;
  const int wave = t >> 6, lane = t & 63;
  const int wm = wave >> 1, wn = wave & 1;
  const int lr = lane & 15, lk = lane >> 4;
  const int grow = wave * 16 + (lane >> 2);  // 0..63 staging row
  const int gk = (lane & 3) * 8;             // staging k offset (elems)

  f32x4 acc[4][4] = {};

  for (int kt = 0; kt < K; kt += 32) {
    __syncthreads();  // previous tile's readers done
    gload16(&A[(size_t)(m0 + grow) * K + kt + gk],      &lA[(wave * 16) * 32]);
    gload16(&A[(size_t)(m0 + 64 + grow) * K + kt + gk], &lA[(64 + wave * 16) * 32]);
    gload16(&Bt[(size_t)(n0 + grow) * K + kt + gk],      &lB[(wave * 16) * 32]);
    gload16(&Bt[(size_t)(n0 + 64 + grow) * K + kt + gk], &lB[(64 + wave * 16) * 32]);
    __syncthreads();  // vmcnt drained -> tile ready
    bf16x8 af[4], bfr[4];
#pragma unroll
    for (int i = 0; i < 4; ++i) {
      af[i]  = *reinterpret_cast<const bf16x8*>(&lA[(wm * 64 + i * 16 + lr) * 32 + lk * 8]);
      bfr[i] = *reinterpret_cast<const bf16x8*>(&lB[(wn * 64 + i * 16 + lr) * 32 + lk * 8]);
    }
#pragma unroll
    for (int i = 0; i < 4; ++i)
#pragma unroll
      for (int j = 0; j < 4; ++j)
        acc[i][j] = __builtin_amdgcn_mfma_f32_16x16x32_bf16(af[i], bfr[j], acc[i][j], 0, 0, 0);
  }

#pragma unroll
  for (int i = 0; i < 4; ++i) {
#pragma unroll
    for (int j = 0; j < 4; ++j) {
#pragma unroll
      for (int r = 0; r < 4; ++r) {
        int gr = m0 + wm * 64 + i * 16 + (lane >> 4) * 4 + r;
        int gc = n0 + wn * 64 + j * 16 + (lane & 15);
        float v = acc[i][j][r];
        if constexpr (EPI == 0) {
          int part = gc >> 11, cc = gc & 2047;
          int head = cc >> 7, d = cc & 127;
          int b = gr >> 11, tt = gr & 2047;
          out_bf[(size_t)part * M * DM + (((size_t)(b * NH + head) * T + tt) * HD + d)] = f2b(v);
        } else if constexpr (EPI == 1) {
          out_bf[(size_t)gr * Ndim + gc] = f2b(v);
        } else if constexpr (EPI == 2) {
          v += bias[gc];
          v = 0.5f * v * (1.0f + erff(v * 0.7071067811865475f));
          out_bf[(size_t)gr * Ndim + gc] = f2b(v);
        } else if constexpr (EPI == 3) {
          v += bias[gc] + resid_f32[(size_t)gr * Ndim + gc] + b2f(resid_bf[(size_t)gr * Ndim + gc]);
          out_f32[(size_t)gr * Ndim + gc] = v;
        } else {  // EPI 4: V^T
          int hh = gr >> 7, d = gr & 127;
          int b = gc >> 11, tt = gc & 2047;
          out_bf[((size_t)(b * NH + hh) * HD + d) * T + tt] = f2b(v);
        }
      }
    }
  }
}

// ---------------- attention ----------------
// grid (T/64, B*NH); 4 waves, each owns 16 q-rows; KV tiles of 64; causal flash.
// K staged [64][128] (256B rows), V^T staged [128][64] (128B rows); both via
// global_load_lds with pre-swizzled SOURCE (linear LDS dest) + swizzled reads.
__global__ __launch_bounds__(256) void attn_fwd(
    const u16* __restrict__ qg, const u16* __restrict__ kg,
    const u16* __restrict__ vt, u16* __restrict__ outg) {
  __shared__ __align__(16) u16 lK[64 * 128];    // 16 KB
  __shared__ __align__(16) u16 lVt[128 * 64];   // 16 KB
  __shared__ __align__(16) u16 lP[4][16 * 72];
  const int t = threadIdx.x;
  const int qi = blockIdx.x, bh = blockIdx.y;
  const int wv = t >> 6, lane = t & 63;
  const int lc = lane & 15, lg = lane >> 4;
  const size_t base = (size_t)bh * T * HD;   // for q, k: [T][HD]
  const size_t vbase = (size_t)bh * HD * T;  // for vt:   [HD][T]
  const int q0 = qi * 64;

  bf16x8 qf[4];
#pragma unroll
  for (int kk = 0; kk < 4; ++kk)
    qf[kk] = *reinterpret_cast<const bf16x8*>(
        &qg[base + (size_t)(q0 + wv * 16 + lc) * HD + kk * 32 + lg * 8]);

  f32x4 oacc[8] = {};
  float mrow[4], lrow[4];
#pragma unroll
  for (int r = 0; r < 4; ++r) { mrow[r] = -INFINITY; lrow[r] = 0.f; }

  // 1/sqrt(128) * log2(e): softmax in base 2 (v_exp_f32 is native 2^x)
  const float scaleL = 0.08838834764831845f * 1.4426950408889634f;
  const int ntiles = qi + 1;
  for (int kt = 0; kt < ntiles; ++kt) {
    __syncthreads();
    // K: 4 gload calls, rows 256B; source pre-swizzled by ((row&7)<<4)
#pragma unroll
    for (int h = 0; h < 4; ++h) {
      int row = h * 16 + wv * 4 + (lane >> 4);
      int sb = ((lane & 15) * 16) ^ ((row & 7) << 4);
      gload16(&kg[base + (size_t)(kt * 64 + row) * HD + (sb >> 1)],
              (const u16*)((const char*)lK + (h * 256 + wv * 64) * 16));
    }
    // V^T: 4 gload calls, rows 128B
#pragma unroll
    for (int h = 0; h < 4; ++h) {
      int row = h * 32 + wv * 8 + (lane >> 3);
      int sb = ((lane & 7) * 16) ^ ((row & 7) << 4);
      gload16(&vt[vbase + (size_t)row * T + kt * 64 + (sb >> 1)],
              (const u16*)((const char*)lVt + (h * 256 + wv * 64) * 16));
    }
    __syncthreads();

    // S = Q K^T
    f32x4 s[4] = {};
#pragma unroll
    for (int nf = 0; nf < 4; ++nf) {
      int krow = nf * 16 + lc;
#pragma unroll
      for (int kk = 0; kk < 4; ++kk) {
        int dbyte = kk * 64 + lg * 16;
        bf16x8 kf = *reinterpret_cast<const bf16x8*>(
            reinterpret_cast<const char*>(lK) + krow * 256 + (dbyte ^ ((krow & 7) << 4)));
        s[nf] = __builtin_amdgcn_mfma_f32_16x16x32_bf16(qf[kk], kf, s[nf], 0, 0, 0);
      }
    }

    // scale (log2 domain) + causal mask + row stats
    float rmax[4];
#pragma unroll
    for (int r = 0; r < 4; ++r) rmax[r] = -INFINITY;
#pragma unroll
    for (int nf = 0; nf < 4; ++nf) {
      int col = kt * 64 + nf * 16 + lc;
#pragma unroll
      for (int r = 0; r < 4; ++r) {
        int row = q0 + wv * 16 + lg * 4 + r;
        float sv = s[nf][r] * scaleL;
        if (col > row) sv = -INFINITY;
        s[nf][r] = sv;
        rmax[r] = fmaxf(rmax[r], sv);
      }
    }
#pragma unroll
    for (int mk = 1; mk < 16; mk <<= 1)
#pragma unroll
      for (int r = 0; r < 4; ++r)
        rmax[r] = fmaxf(rmax[r], __shfl_xor(rmax[r], mk));
    float corr[4];
#pragma unroll
    for (int r = 0; r < 4; ++r) {
      float mnew = fmaxf(mrow[r], rmax[r]);
      corr[r] = exp2f(mrow[r] - mnew);
      mrow[r] = mnew;
      lrow[r] *= corr[r];
    }
#pragma unroll
    for (int dc = 0; dc < 8; ++dc)
#pragma unroll
      for (int r = 0; r < 4; ++r) oacc[dc][r] *= corr[r];

    // P = 2^(s - m) -> lP (per-wave, padded)
#pragma unroll
    for (int nf = 0; nf < 4; ++nf) {
#pragma unroll
      for (int r = 0; r < 4; ++r) {
        float p = exp2f(s[nf][r] - mrow[r]);
        lrow[r] += p;
        lP[wv][(lg * 4 + r) * 72 + nf * 16 + lc] = f2b(p);
      }
    }
    bf16x8 pa[2];
#pragma unroll
    for (int kk = 0; kk < 2; ++kk)
      pa[kk] = *reinterpret_cast<const bf16x8*>(&lP[wv][lc * 72 + kk * 32 + lg * 8]);
#pragma unroll
    for (int dc = 0; dc < 8; ++dc) {
#pragma unroll
      for (int kk = 0; kk < 2; ++kk) {
        int vrow = dc * 16 + lc;
        int off = (kk * 64 + lg * 16) ^ ((vrow & 7) << 4);
        bf16x8 vf = *reinterpret_cast<const bf16x8*>(
            reinterpret_cast<const char*>(lVt) + vrow * 128 + off);
        oacc[dc] = __builtin_amdgcn_mfma_f32_16x16x32_bf16(pa[kk], vf, oacc[dc], 0, 0, 0);
      }
    }
  }

#pragma unroll
  for (int mk = 1; mk < 16; mk <<= 1)
#pragma unroll
    for (int r = 0; r < 4; ++r) lrow[r] += __shfl_xor(lrow[r], mk);

  const int b = bh >> 4, hh = bh & 15;
#pragma unroll
  for (int dc = 0; dc < 8; ++dc)
#pragma unroll
    for (int r = 0; r < 4; ++r) {
      int tt = q0 + wv * 16 + lg * 4 + r;
      int d = dc * 16 + lc;
      float o = oacc[dc][r] / lrow[r];
      outg[(size_t)(b * T + tt) * DM + hh * HD + d] = f2b(o);
    }
}

// ---------------- launch ----------------

extern "C" void kernel_launch(void* const* d_in, const int* in_sizes, int n_in,
                              void* d_out, int out_size, void* d_ws, size_t ws_size,
                              hipStream_t stream) {
  const float* x      = (const float*)d_in[0];
  const float* w_qkv  = (const float*)d_in[1];
  const float* w_proj = (const float*)d_in[2];
  const float* w_ff1  = (const float*)d_in[3];
  const float* b_ff1  = (const float*)d_in[4];
  const float* w_ff2  = (const float*)d_in[5];
  const float* b_ff2  = (const float*)d_in[6];
  float* out = (float*)d_out;

  u16* ws = (u16*)d_ws;
  size_t o = 0;
  u16* x_bf      = ws + o; o += (size_t)M * DM;
  u16* wqkv_t    = ws + o; o += (size_t)NQKV * DM;
  u16* wproj_t   = ws + o; o += (size_t)DM * DM;
  u16* wff1_t    = ws + o; o += (size_t)FF * DM;
  u16* wff2_t    = ws + o; o += (size_t)DM * FF;
  u16* attn_proj = ws + o; o += (size_t)M * DM;
  u16* qbuf      = ws + o;                    // q,k,vt,attn_out contiguous
  u16* kbuf      = qbuf + (size_t)M * DM;
  u16* vtbuf     = kbuf + (size_t)M * DM;     // V^T: [B][H][HD][T]
  u16* attn_out  = vtbuf + (size_t)M * DM;
  u16* hbuf      = qbuf;                      // aliases q|k|vt|attn_out = M*FF elems

  // conversions
  cvt_f32_to_bf16<<<(M * DM / 4 + 255) / 256, 256, 0, stream>>>(x, x_bf, M * DM / 4);
  transpose_cvt<<<dim3(NQKV / 32, DM / 32), 256, 0, stream>>>(w_qkv, wqkv_t, DM, NQKV);
  transpose_cvt<<<dim3(DM / 32, DM / 32), 256, 0, stream>>>(w_proj, wproj_t, DM, DM);
  transpose_cvt<<<dim3(FF / 32, DM / 32), 256, 0, stream>>>(w_ff1, wff1_t, DM, FF);
  transpose_cvt<<<dim3(DM / 32, FF / 32), 256, 0, stream>>>(w_ff2, wff2_t, FF, DM);

  // q,k projection (scatter into q/k) — first 4096 output cols of qkv
  gemm_bf16<0><<<dim3(4096 / 128, M / 128), 256, 0, stream>>>(
      x_bf, wqkv_t, 4096, DM, qbuf, nullptr, nullptr, nullptr, nullptr);

  // V^T = Wv^T X^T: A = V-rows of wqkv_t [2048][2048], Bt = x_bf [4096][2048]
  gemm_bf16<4><<<dim3(M / 128, DM / 128), 256, 0, stream>>>(
      wqkv_t + (size_t)4096 * DM, x_bf, M, DM, vtbuf, nullptr, nullptr, nullptr, nullptr);

  // causal flash attention
  attn_fwd<<<dim3(T / 64, BB * NH), 256, 0, stream>>>(qbuf, kbuf, vtbuf, attn_out);

  // output projection
  gemm_bf16<1><<<dim3(DM / 128, M / 128), 256, 0, stream>>>(
      attn_out, wproj_t, DM, DM, attn_proj, nullptr, nullptr, nullptr, nullptr);

  // FF1 + GELU (hbuf overwrites q/k/vt/attn_out — all consumed by now)
  gemm_bf16<2><<<dim3(FF / 128, M / 128), 256, 0, stream>>>(
      x_bf, wff1_t, FF, DM, hbuf, nullptr, b_ff1, nullptr, nullptr);

  // FF2 + bias + residuals -> f32 out
  gemm_bf16<3><<<dim3(DM / 128, M / 128), 256, 0, stream>>>(
      hbuf, wff2_t, DM, FF, nullptr, out, b_ff2, x, attn_proj);
}

// Round 4
// 730.095 us; speedup vs baseline: 1.2603x; 1.1847x over previous
//
#include <hip/hip_runtime.h>
#include <hip/hip_bf16.h>
#include <cmath>

typedef __bf16 bf16x8 __attribute__((ext_vector_type(8)));
typedef float f32x4 __attribute__((ext_vector_type(4)));
typedef unsigned short u16;
typedef unsigned int u32;

#define DEV __device__ __forceinline__

static constexpr int BB = 2;
static constexpr int T = 2048;
static constexpr int DM = 2048;
static constexpr int NH = 16;
static constexpr int HD = 128;
static constexpr int FF = 8192;
static constexpr int M = BB * T;      // 4096
static constexpr int NQKV = 3 * DM;   // 6144

DEV u16 f2b(float f) {
  u32 u = __builtin_bit_cast(u32, f);
  u = (u + 0x7FFFu + ((u >> 16) & 1u)) >> 16;
  return (u16)u;
}
DEV float b2f(u16 h) {
  u32 u = ((u32)h) << 16;
  return __builtin_bit_cast(float, u);
}

// async global->LDS, 16B per lane; LDS dest = wave-uniform base + lane*16
DEV void gload16(const u16* g, const u16* l) {
  __builtin_amdgcn_global_load_lds(
      (const __attribute__((address_space(1))) void*)(uintptr_t)g,
      (__attribute__((address_space(3))) void*)(unsigned)(uintptr_t)l,
      16, 0, 0);
}

// ---------------- conversions ----------------

__global__ void cvt_f32_to_bf16(const float* __restrict__ in, u16* __restrict__ out, int n4) {
  int i = blockIdx.x * blockDim.x + threadIdx.x;
  if (i >= n4) return;
  float4 v = reinterpret_cast<const float4*>(in)[i];
  ushort4 o;
  o.x = f2b(v.x); o.y = f2b(v.y); o.z = f2b(v.z); o.w = f2b(v.w);
  reinterpret_cast<ushort4*>(out)[i] = o;
}

// W [K][N] f32  ->  Wt [N][K] bf16
__global__ void transpose_cvt(const float* __restrict__ W, u16* __restrict__ Wt, int K, int N) {
  __shared__ float tile[32][33];
  int nb = blockIdx.x * 32, kb = blockIdx.y * 32;
  int tx = threadIdx.x & 31, ty = threadIdx.x >> 5;  // ty 0..7
#pragma unroll
  for (int r = 0; r < 32; r += 8)
    tile[ty + r][tx] = W[(size_t)(kb + ty + r) * N + nb + tx];
  __syncthreads();
#pragma unroll
  for (int r = 0; r < 32; r += 8)
    Wt[(size_t)(nb + ty + r) * K + kb + tx] = f2b(tile[tx][ty + r]);
}

// ---------------- GEMM ----------------
// C[M][N] = A[M][K] * Bt[N][K]^T, bf16 inputs, f32 accum.
// 3-buffer LDS pipeline: stage tile t+2 while computing t; counted vmcnt(4)
// (never 0 in steady state) + RAW s_barrier (no __syncthreads -> no vmcnt(0)
// drain). Buffer (t+3)%3 == (t)%3 is re-staged only after the barrier ending
// tile t's reads.
// EPI 0: scatter qk -> q/k (B,H,T,hd) bf16
// EPI 1: plain bf16 out
// EPI 2: bias + tanh-GELU, bf16 out
// EPI 3: bias + resid_f32 + resid_bf, f32 out
// EPI 4: V^T scatter: out[((b*NH+h)*HD+d)*T + t]
template <int EPI>
__global__ __launch_bounds__(256) void gemm_bf16(
    const u16* __restrict__ A, const u16* __restrict__ Bt, int Ndim, int K,
    u16* __restrict__ out_bf, float* __restrict__ out_f32,
    const float* __restrict__ bias,
    const float* __restrict__ resid_f32, const u16* __restrict__ resid_bf) {
  __shared__ __align__(16) u16 lds[3 * 2 * 128 * 32];  // 48 KB: 3 bufs x (A,B) x 128x32
  const int t = threadIdx.x;
  const int m0 = blockIdx.y * 128, n0 = blockIdx.x * 128;
  const int wave = t >> 6, lane = t & 63;
  const int wm = wave >> 1, wn = wave & 1;
  const int lr = lane & 15, lk = lane >> 4;
  const int grow = wave * 16 + (lane >> 2);  // 0..63 staging row
  const int gk = (lane & 3) * 8;             // staging k offset (elems)

  // rotating buffer pointers: compute / next / stage
  u16* cA = lds;                 u16* cB = lds + 4096;
  u16* nA = lds + 2 * 4096;      u16* nB = lds + 3 * 4096;
  u16* sA = lds + 4 * 4096;      u16* sB = lds + 5 * 4096;

  // per-thread global staging pointers (advance 32 elems per staged tile)
  const u16* gA0 = &A[(size_t)(m0 + grow) * K + gk];
  const u16* gA1 = &A[(size_t)(m0 + 64 + grow) * K + gk];
  const u16* gB0 = &Bt[(size_t)(n0 + grow) * K + gk];
  const u16* gB1 = &Bt[(size_t)(n0 + 64 + grow) * K + gk];

  const int wb = wave * 16 * 32;  // wave's LDS staging base (elems)

  auto stage = [&](u16* dA, u16* dB) {
    gload16(gA0, dA + wb);
    gload16(gA1, dA + 64 * 32 + wb);
    gload16(gB0, dB + wb);
    gload16(gB1, dB + 64 * 32 + wb);
    gA0 += 32; gA1 += 32; gB0 += 32; gB1 += 32;
  };

  const int NT = K >> 5;  // K/32 tiles (>= 3 for all our shapes)

  // prologue: stage tiles 0,1; wait tile 0 (tile 1's 4 loads stay in flight)
  stage(cA, cB);
  stage(nA, nB);
  __builtin_amdgcn_sched_barrier(0);
  asm volatile("s_waitcnt vmcnt(4)" ::: "memory");
  __builtin_amdgcn_s_barrier();
  __builtin_amdgcn_sched_barrier(0);

  f32x4 acc[4][4] = {};

  for (int kt = 0; kt < NT; ++kt) {
    if (kt + 2 < NT) stage(sA, sB);
    bf16x8 af[4], bfr[4];
#pragma unroll
    for (int i = 0; i < 4; ++i) {
      af[i]  = *reinterpret_cast<const bf16x8*>(&cA[(wm * 64 + i * 16 + lr) * 32 + lk * 8]);
      bfr[i] = *reinterpret_cast<const bf16x8*>(&cB[(wn * 64 + i * 16 + lr) * 32 + lk * 8]);
    }
#pragma unroll
    for (int i = 0; i < 4; ++i)
#pragma unroll
      for (int j = 0; j < 4; ++j)
        acc[i][j] = __builtin_amdgcn_mfma_f32_16x16x32_bf16(af[i], bfr[j], acc[i][j], 0, 0, 0);
    if (kt + 1 < NT) {
      __builtin_amdgcn_sched_barrier(0);
      if (kt + 2 < NT) asm volatile("s_waitcnt vmcnt(4)" ::: "memory");
      else             asm volatile("s_waitcnt vmcnt(0)" ::: "memory");
      __builtin_amdgcn_s_barrier();
      __builtin_amdgcn_sched_barrier(0);
      u16* tA = cA; u16* tB = cB;
      cA = nA; cB = nB; nA = sA; nB = sB; sA = tA; sB = tB;
    }
  }

#pragma unroll
  for (int i = 0; i < 4; ++i) {
#pragma unroll
    for (int j = 0; j < 4; ++j) {
#pragma unroll
      for (int r = 0; r < 4; ++r) {
        int gr = m0 + wm * 64 + i * 16 + (lane >> 4) * 4 + r;
        int gc = n0 + wn * 64 + j * 16 + (lane & 15);
        float v = acc[i][j][r];
        if constexpr (EPI == 0) {
          int part = gc >> 11, cc = gc & 2047;
          int head = cc >> 7, d = cc & 127;
          int b = gr >> 11, tt = gr & 2047;
          out_bf[(size_t)part * M * DM + (((size_t)(b * NH + head) * T + tt) * HD + d)] = f2b(v);
        } else if constexpr (EPI == 1) {
          out_bf[(size_t)gr * Ndim + gc] = f2b(v);
        } else if constexpr (EPI == 2) {
          v += bias[gc];
          // tanh-form GELU (error << bf16 tolerance); exp2f -> native v_exp_f32
          float u = v * (v * v * 0.044715f + 1.0f) * 0.7978845608028654f;
          float e = exp2f(u * 2.885390081777927f);  // e^(2u)
          float th = 1.0f - 2.0f / (e + 1.0f);
          v = 0.5f * v * (1.0f + th);
          out_bf[(size_t)gr * Ndim + gc] = f2b(v);
        } else if constexpr (EPI == 3) {
          v += bias[gc] + resid_f32[(size_t)gr * Ndim + gc] + b2f(resid_bf[(size_t)gr * Ndim + gc]);
          out_f32[(size_t)gr * Ndim + gc] = v;
        } else {  // EPI 4: V^T
          int hh = gr >> 7, d = gr & 127;
          int b = gc >> 11, tt = gc & 2047;
          out_bf[((size_t)(b * NH + hh) * HD + d) * T + tt] = f2b(v);
        }
      }
    }
  }
}

// ---------------- attention ----------------
// grid (T/64, B*NH); 4 waves, each owns 16 q-rows; KV tiles of 64; causal flash.
// K staged [64][128] (256B rows), V^T staged [128][64] (128B rows); both via
// global_load_lds with pre-swizzled SOURCE (linear LDS dest) + swizzled reads.
__global__ __launch_bounds__(256) void attn_fwd(
    const u16* __restrict__ qg, const u16* __restrict__ kg,
    const u16* __restrict__ vt, u16* __restrict__ outg) {
  __shared__ __align__(16) u16 lK[64 * 128];    // 16 KB
  __shared__ __align__(16) u16 lVt[128 * 64];   // 16 KB
  __shared__ __align__(16) u16 lP[4][16 * 72];
  const int t = threadIdx.x;
  const int qi = blockIdx.x, bh = blockIdx.y;
  const int wv = t >> 6, lane = t & 63;
  const int lc = lane & 15, lg = lane >> 4;
  const size_t base = (size_t)bh * T * HD;   // for q, k: [T][HD]
  const size_t vbase = (size_t)bh * HD * T;  // for vt:   [HD][T]
  const int q0 = qi * 64;

  bf16x8 qf[4];
#pragma unroll
  for (int kk = 0; kk < 4; ++kk)
    qf[kk] = *reinterpret_cast<const bf16x8*>(
        &qg[base + (size_t)(q0 + wv * 16 + lc) * HD + kk * 32 + lg * 8]);

  f32x4 oacc[8] = {};
  float mrow[4], lrow[4];
#pragma unroll
  for (int r = 0; r < 4; ++r) { mrow[r] = -INFINITY; lrow[r] = 0.f; }

  // 1/sqrt(128) * log2(e): softmax in base 2 (v_exp_f32 is native 2^x)
  const float scaleL = 0.08838834764831845f * 1.4426950408889634f;
  const int ntiles = qi + 1;
  for (int kt = 0; kt < ntiles; ++kt) {
    __syncthreads();
    // K: 4 gload calls, rows 256B; source pre-swizzled by ((row&7)<<4)
#pragma unroll
    for (int h = 0; h < 4; ++h) {
      int row = h * 16 + wv * 4 + (lane >> 4);
      int sb = ((lane & 15) * 16) ^ ((row & 7) << 4);
      gload16(&kg[base + (size_t)(kt * 64 + row) * HD + (sb >> 1)],
              (const u16*)((const char*)lK + (h * 256 + wv * 64) * 16));
    }
    // V^T: 4 gload calls, rows 128B
#pragma unroll
    for (int h = 0; h < 4; ++h) {
      int row = h * 32 + wv * 8 + (lane >> 3);
      int sb = ((lane & 7) * 16) ^ ((row & 7) << 4);
      gload16(&vt[vbase + (size_t)row * T + kt * 64 + (sb >> 1)],
              (const u16*)((const char*)lVt + (h * 256 + wv * 64) * 16));
    }
    __syncthreads();

    // S = Q K^T
    f32x4 s[4] = {};
#pragma unroll
    for (int nf = 0; nf < 4; ++nf) {
      int krow = nf * 16 + lc;
#pragma unroll
      for (int kk = 0; kk < 4; ++kk) {
        int dbyte = kk * 64 + lg * 16;
        bf16x8 kf = *reinterpret_cast<const bf16x8*>(
            reinterpret_cast<const char*>(lK) + krow * 256 + (dbyte ^ ((krow & 7) << 4)));
        s[nf] = __builtin_amdgcn_mfma_f32_16x16x32_bf16(qf[kk], kf, s[nf], 0, 0, 0);
      }
    }

    // scale (log2 domain) + causal mask + row stats
    float rmax[4];
#pragma unroll
    for (int r = 0; r < 4; ++r) rmax[r] = -INFINITY;
#pragma unroll
    for (int nf = 0; nf < 4; ++nf) {
      int col = kt * 64 + nf * 16 + lc;
#pragma unroll
      for (int r = 0; r < 4; ++r) {
        int row = q0 + wv * 16 + lg * 4 + r;
        float sv = s[nf][r] * scaleL;
        if (col > row) sv = -INFINITY;
        s[nf][r] = sv;
        rmax[r] = fmaxf(rmax[r], sv);
      }
    }
#pragma unroll
    for (int mk = 1; mk < 16; mk <<= 1)
#pragma unroll
      for (int r = 0; r < 4; ++r)
        rmax[r] = fmaxf(rmax[r], __shfl_xor(rmax[r], mk));
    float corr[4];
#pragma unroll
    for (int r = 0; r < 4; ++r) {
      float mnew = fmaxf(mrow[r], rmax[r]);
      corr[r] = exp2f(mrow[r] - mnew);
      mrow[r] = mnew;
      lrow[r] *= corr[r];
    }
#pragma unroll
    for (int dc = 0; dc < 8; ++dc)
#pragma unroll
      for (int r = 0; r < 4; ++r) oacc[dc][r] *= corr[r];

    // P = 2^(s - m) -> lP (per-wave, padded)
#pragma unroll
    for (int nf = 0; nf < 4; ++nf) {
#pragma unroll
      for (int r = 0; r < 4; ++r) {
        float p = exp2f(s[nf][r] - mrow[r]);
        lrow[r] += p;
        lP[wv][(lg * 4 + r) * 72 + nf * 16 + lc] = f2b(p);
      }
    }
    bf16x8 pa[2];
#pragma unroll
    for (int kk = 0; kk < 2; ++kk)
      pa[kk] = *reinterpret_cast<const bf16x8*>(&lP[wv][lc * 72 + kk * 32 + lg * 8]);
#pragma unroll
    for (int dc = 0; dc < 8; ++dc) {
#pragma unroll
      for (int kk = 0; kk < 2; ++kk) {
        int vrow = dc * 16 + lc;
        int off = (kk * 64 + lg * 16) ^ ((vrow & 7) << 4);
        bf16x8 vf = *reinterpret_cast<const bf16x8*>(
            reinterpret_cast<const char*>(lVt) + vrow * 128 + off);
        oacc[dc] = __builtin_amdgcn_mfma_f32_16x16x32_bf16(pa[kk], vf, oacc[dc], 0, 0, 0);
      }
    }
  }

#pragma unroll
  for (int mk = 1; mk < 16; mk <<= 1)
#pragma unroll
    for (int r = 0; r < 4; ++r) lrow[r] += __shfl_xor(lrow[r], mk);

  const int b = bh >> 4, hh = bh & 15;
#pragma unroll
  for (int dc = 0; dc < 8; ++dc)
#pragma unroll
    for (int r = 0; r < 4; ++r) {
      int tt = q0 + wv * 16 + lg * 4 + r;
      int d = dc * 16 + lc;
      float o = oacc[dc][r] / lrow[r];
      outg[(size_t)(b * T + tt) * DM + hh * HD + d] = f2b(o);
    }
}

// ---------------- launch ----------------

extern "C" void kernel_launch(void* const* d_in, const int* in_sizes, int n_in,
                              void* d_out, int out_size, void* d_ws, size_t ws_size,
                              hipStream_t stream) {
  const float* x      = (const float*)d_in[0];
  const float* w_qkv  = (const float*)d_in[1];
  const float* w_proj = (const float*)d_in[2];
  const float* w_ff1  = (const float*)d_in[3];
  const float* b_ff1  = (const float*)d_in[4];
  const float* w_ff2  = (const float*)d_in[5];
  const float* b_ff2  = (const float*)d_in[6];
  float* out = (float*)d_out;

  u16* ws = (u16*)d_ws;
  size_t o = 0;
  u16* x_bf      = ws + o; o += (size_t)M * DM;
  u16* wqkv_t    = ws + o; o += (size_t)NQKV * DM;
  u16* wproj_t   = ws + o; o += (size_t)DM * DM;
  u16* wff1_t    = ws + o; o += (size_t)FF * DM;
  u16* wff2_t    = ws + o; o += (size_t)DM * FF;
  u16* attn_proj = ws + o; o += (size_t)M * DM;
  u16* qbuf      = ws + o;                    // q,k,vt,attn_out contiguous
  u16* kbuf      = qbuf + (size_t)M * DM;
  u16* vtbuf     = kbuf + (size_t)M * DM;     // V^T: [B][H][HD][T]
  u16* attn_out  = vtbuf + (size_t)M * DM;
  u16* hbuf      = qbuf;                      // aliases q|k|vt|attn_out = M*FF elems

  // conversions
  cvt_f32_to_bf16<<<(M * DM / 4 + 255) / 256, 256, 0, stream>>>(x, x_bf, M * DM / 4);
  transpose_cvt<<<dim3(NQKV / 32, DM / 32), 256, 0, stream>>>(w_qkv, wqkv_t, DM, NQKV);
  transpose_cvt<<<dim3(DM / 32, DM / 32), 256, 0, stream>>>(w_proj, wproj_t, DM, DM);
  transpose_cvt<<<dim3(FF / 32, DM / 32), 256, 0, stream>>>(w_ff1, wff1_t, DM, FF);
  transpose_cvt<<<dim3(DM / 32, FF / 32), 256, 0, stream>>>(w_ff2, wff2_t, FF, DM);

  // q,k projection (scatter into q/k) — first 4096 output cols of qkv
  gemm_bf16<0><<<dim3(4096 / 128, M / 128), 256, 0, stream>>>(
      x_bf, wqkv_t, 4096, DM, qbuf, nullptr, nullptr, nullptr, nullptr);

  // V^T = Wv^T X^T: A = V-rows of wqkv_t [2048][2048], Bt = x_bf [4096][2048]
  gemm_bf16<4><<<dim3(M / 128, DM / 128), 256, 0, stream>>>(
      wqkv_t + (size_t)4096 * DM, x_bf, M, DM, vtbuf, nullptr, nullptr, nullptr, nullptr);

  // causal flash attention
  attn_fwd<<<dim3(T / 64, BB * NH), 256, 0, stream>>>(qbuf, kbuf, vtbuf, attn_out);

  // output projection
  gemm_bf16<1><<<dim3(DM / 128, M / 128), 256, 0, stream>>>(
      attn_out, wproj_t, DM, DM, attn_proj, nullptr, nullptr, nullptr, nullptr);

  // FF1 + GELU (hbuf overwrites q/k/vt/attn_out — all consumed by now)
  gemm_bf16<2><<<dim3(FF / 128, M / 128), 256, 0, stream>>>(
      x_bf, wff1_t, FF, DM, hbuf, nullptr, b_ff1, nullptr, nullptr);

  // FF2 + bias + residuals -> f32 out
  gemm_bf16<3><<<dim3(DM / 128, M / 128), 256, 0, stream>>>(
      hbuf, wff2_t, DM, FF, nullptr, out, b_ff2, x, attn_proj);
}

// Round 5
// 691.086 us; speedup vs baseline: 1.3315x; 1.0564x over previous
//
#include <hip/hip_runtime.h>
#include <hip/hip_bf16.h>
#include <cmath>

typedef __bf16 bf16x8 __attribute__((ext_vector_type(8)));
typedef float f32x4 __attribute__((ext_vector_type(4)));
typedef unsigned short u16;
typedef unsigned int u32;

#define DEV __device__ __forceinline__

static constexpr int BB = 2;
static constexpr int T = 2048;
static constexpr int DM = 2048;
static constexpr int NH = 16;
static constexpr int HD = 128;
static constexpr int FF = 8192;
static constexpr int M = BB * T;      // 4096
static constexpr int NQKV = 3 * DM;   // 6144

DEV u16 f2b(float f) {
  u32 u = __builtin_bit_cast(u32, f);
  u = (u + 0x7FFFu + ((u >> 16) & 1u)) >> 16;
  return (u16)u;
}
DEV float b2f(u16 h) {
  u32 u = ((u32)h) << 16;
  return __builtin_bit_cast(float, u);
}

// async global->LDS, 16B per lane; LDS dest = wave-uniform base + lane*16
DEV void gload16(const u16* g, const u16* l) {
  __builtin_amdgcn_global_load_lds(
      (const __attribute__((address_space(1))) void*)(uintptr_t)g,
      (__attribute__((address_space(3))) void*)(unsigned)(uintptr_t)l,
      16, 0, 0);
}

// ---------------- conversions ----------------

__global__ void cvt_f32_to_bf16(const float* __restrict__ in, u16* __restrict__ out, int n4) {
  int i = blockIdx.x * blockDim.x + threadIdx.x;
  if (i >= n4) return;
  float4 v = reinterpret_cast<const float4*>(in)[i];
  ushort4 o;
  o.x = f2b(v.x); o.y = f2b(v.y); o.z = f2b(v.z); o.w = f2b(v.w);
  reinterpret_cast<ushort4*>(out)[i] = o;
}

// W [K][N] f32  ->  Wt [N][K] bf16
__global__ void transpose_cvt(const float* __restrict__ W, u16* __restrict__ Wt, int K, int N) {
  __shared__ float tile[32][33];
  int nb = blockIdx.x * 32, kb = blockIdx.y * 32;
  int tx = threadIdx.x & 31, ty = threadIdx.x >> 5;  // ty 0..7
#pragma unroll
  for (int r = 0; r < 32; r += 8)
    tile[ty + r][tx] = W[(size_t)(kb + ty + r) * N + nb + tx];
  __syncthreads();
#pragma unroll
  for (int r = 0; r < 32; r += 8)
    Wt[(size_t)(nb + ty + r) * K + kb + tx] = f2b(tile[tx][ty + r]);
}

// ---------------- GEMM ----------------
// C[M][N] = A[M][K] * Bt[N][K]^T, bf16 inputs, f32 accum.
// 256x128 tile, 8 waves (4m x 2n), BK=32. 3-buffer LDS pipeline with counted
// vmcnt(3) (stage tile t+2 while computing t; buffer free since its barrier)
// + raw s_barrier (no vmcnt(0) drain). 1D grid + bijective XCD swizzle
// (all launches have nwg % 8 == 0).
// EPI 0: scatter qk -> q/k (B,H,T,hd) bf16
// EPI 1: plain bf16 out
// EPI 2: bias + tanh-GELU, bf16 out
// EPI 3: bias + resid_f32 + resid_bf, f32 out
// EPI 4: V^T scatter: out[((b*NH+h)*HD+d)*T + t]
template <int EPI>
__global__ __launch_bounds__(512, 4) void gemm_bf16(
    const u16* __restrict__ A, const u16* __restrict__ Bt, int Ndim, int K, int gx,
    u16* __restrict__ out_bf, float* __restrict__ out_f32,
    const float* __restrict__ bias,
    const float* __restrict__ resid_f32, const u16* __restrict__ resid_bf) {
  __shared__ __align__(16) u16 lds[3 * (256 + 128) * 32];  // 72 KB
  const int t = threadIdx.x;
  // XCD-bijective swizzle: consecutive wg on one XCD share A-panels
  const int nwg = gridDim.x, cpx = nwg >> 3;
  const int wg = (blockIdx.x & 7) * cpx + (blockIdx.x >> 3);
  const int m0 = (wg / gx) * 256, n0 = (wg % gx) * 128;
  const int wave = t >> 6, lane = t & 63;
  const int wm = wave >> 1, wn = wave & 1;     // 4 x 2 wave grid, 64x64 each
  const int lr = lane & 15, lk = lane >> 4;

  // rotating buffers: each = A[256][32] + B[128][32]
  u16* cA = lds;                   u16* cB = lds + 8192;
  u16* nA = lds + 12288;           u16* nB = lds + 12288 + 8192;
  u16* sA = lds + 2 * 12288;       u16* sB = lds + 2 * 12288 + 8192;

  // per-thread global staging pointers (advance 32 elems per staged tile)
  const u16* gA0 = &A[(size_t)(m0 + wave * 16 + (lane >> 2)) * K + (lane & 3) * 8];
  const u16* gA1 = gA0 + (size_t)128 * K;
  const u16* gB0 = &Bt[(size_t)(n0 + wave * 16 + (lane >> 2)) * K + (lane & 3) * 8];

  const int wbase = wave * 512;  // wave's 16-row chunk (16*32 elems)

  auto stage = [&](u16* dA, u16* dB) {
    gload16(gA0, dA + wbase);
    gload16(gA1, dA + 4096 + wbase);
    gload16(gB0, dB + wbase);
    gA0 += 32; gA1 += 32; gB0 += 32;
  };

  const int NT = K >> 5;

  stage(cA, cB);
  stage(nA, nB);
  __builtin_amdgcn_sched_barrier(0);
  asm volatile("s_waitcnt vmcnt(3)" ::: "memory");
  __builtin_amdgcn_s_barrier();
  __builtin_amdgcn_sched_barrier(0);

  f32x4 acc[4][4] = {};

  for (int kt = 0; kt < NT; ++kt) {
    if (kt + 2 < NT) stage(sA, sB);
    bf16x8 af[4], bfr[4];
#pragma unroll
    for (int i = 0; i < 4; ++i) {
      af[i]  = *reinterpret_cast<const bf16x8*>(&cA[(wm * 64 + i * 16 + lr) * 32 + lk * 8]);
      bfr[i] = *reinterpret_cast<const bf16x8*>(&cB[(wn * 64 + i * 16 + lr) * 32 + lk * 8]);
    }
#pragma unroll
    for (int i = 0; i < 4; ++i)
#pragma unroll
      for (int j = 0; j < 4; ++j)
        acc[i][j] = __builtin_amdgcn_mfma_f32_16x16x32_bf16(af[i], bfr[j], acc[i][j], 0, 0, 0);
    if (kt + 1 < NT) {
      __builtin_amdgcn_sched_barrier(0);
      if (kt + 2 < NT) asm volatile("s_waitcnt vmcnt(3)" ::: "memory");
      else             asm volatile("s_waitcnt vmcnt(0)" ::: "memory");
      __builtin_amdgcn_s_barrier();
      __builtin_amdgcn_sched_barrier(0);
      u16* tA = cA; u16* tB = cB;
      cA = nA; cB = nB; nA = sA; nB = sB; sA = tA; sB = tB;
    }
  }

#pragma unroll
  for (int i = 0; i < 4; ++i) {
#pragma unroll
    for (int j = 0; j < 4; ++j) {
#pragma unroll
      for (int r = 0; r < 4; ++r) {
        int gr = m0 + wm * 64 + i * 16 + (lane >> 4) * 4 + r;
        int gc = n0 + wn * 64 + j * 16 + (lane & 15);
        float v = acc[i][j][r];
        if constexpr (EPI == 0) {
          int part = gc >> 11, cc = gc & 2047;
          int head = cc >> 7, d = cc & 127;
          int b = gr >> 11, tt = gr & 2047;
          out_bf[(size_t)part * M * DM + (((size_t)(b * NH + head) * T + tt) * HD + d)] = f2b(v);
        } else if constexpr (EPI == 1) {
          out_bf[(size_t)gr * Ndim + gc] = f2b(v);
        } else if constexpr (EPI == 2) {
          v += bias[gc];
          // tanh-form GELU; exp2f -> native v_exp_f32
          float u = v * (v * v * 0.044715f + 1.0f) * 0.7978845608028654f;
          float e = exp2f(u * 2.885390081777927f);  // e^(2u)
          float th = 1.0f - 2.0f / (e + 1.0f);
          v = 0.5f * v * (1.0f + th);
          out_bf[(size_t)gr * Ndim + gc] = f2b(v);
        } else if constexpr (EPI == 3) {
          v += bias[gc] + resid_f32[(size_t)gr * Ndim + gc] + b2f(resid_bf[(size_t)gr * Ndim + gc]);
          out_f32[(size_t)gr * Ndim + gc] = v;
        } else {  // EPI 4: V^T
          int hh = gr >> 7, d = gr & 127;
          int b = gc >> 11, tt = gc & 2047;
          out_bf[((size_t)(b * NH + hh) * HD + d) * T + tt] = f2b(v);
        }
      }
    }
  }
}

// ---------------- attention ----------------
// grid (T/64, B*NH); 4 waves, each owns 16 q-rows; KV tiles of 64; causal flash.
// Longest-first dispatch (qi reversed); defer-max rescale (T13, log2 THR=11.5).
__global__ __launch_bounds__(256) void attn_fwd(
    const u16* __restrict__ qg, const u16* __restrict__ kg,
    const u16* __restrict__ vt, u16* __restrict__ outg) {
  __shared__ __align__(16) u16 lK[64 * 128];    // 16 KB
  __shared__ __align__(16) u16 lVt[128 * 64];   // 16 KB
  __shared__ __align__(16) u16 lP[4][16 * 72];
  const int t = threadIdx.x;
  const int qi = gridDim.x - 1 - blockIdx.x;   // longest blocks first
  const int bh = blockIdx.y;
  const int wv = t >> 6, lane = t & 63;
  const int lc = lane & 15, lg = lane >> 4;
  const size_t base = (size_t)bh * T * HD;   // q, k: [T][HD]
  const size_t vbase = (size_t)bh * HD * T;  // vt:   [HD][T]
  const int q0 = qi * 64;

  bf16x8 qf[4];
#pragma unroll
  for (int kk = 0; kk < 4; ++kk)
    qf[kk] = *reinterpret_cast<const bf16x8*>(
        &qg[base + (size_t)(q0 + wv * 16 + lc) * HD + kk * 32 + lg * 8]);

  f32x4 oacc[8] = {};
  float mrow[4], lrow[4];
#pragma unroll
  for (int r = 0; r < 4; ++r) { mrow[r] = -INFINITY; lrow[r] = 0.f; }

  // 1/sqrt(128) * log2(e): softmax in base 2 (v_exp_f32 is native 2^x)
  const float scaleL = 0.08838834764831845f * 1.4426950408889634f;
  const int ntiles = qi + 1;
  for (int kt = 0; kt < ntiles; ++kt) {
    __syncthreads();
    // K: 4 gload calls, rows 256B; source pre-swizzled by ((row&7)<<4)
#pragma unroll
    for (int h = 0; h < 4; ++h) {
      int row = h * 16 + wv * 4 + (lane >> 4);
      int sb = ((lane & 15) * 16) ^ ((row & 7) << 4);
      gload16(&kg[base + (size_t)(kt * 64 + row) * HD + (sb >> 1)],
              (const u16*)((const char*)lK + (h * 256 + wv * 64) * 16));
    }
    // V^T: 4 gload calls, rows 128B
#pragma unroll
    for (int h = 0; h < 4; ++h) {
      int row = h * 32 + wv * 8 + (lane >> 3);
      int sb = ((lane & 7) * 16) ^ ((row & 7) << 4);
      gload16(&vt[vbase + (size_t)row * T + kt * 64 + (sb >> 1)],
              (const u16*)((const char*)lVt + (h * 256 + wv * 64) * 16));
    }
    __syncthreads();

    // S = Q K^T
    f32x4 s[4] = {};
#pragma unroll
    for (int nf = 0; nf < 4; ++nf) {
      int krow = nf * 16 + lc;
#pragma unroll
      for (int kk = 0; kk < 4; ++kk) {
        int dbyte = kk * 64 + lg * 16;
        bf16x8 kf = *reinterpret_cast<const bf16x8*>(
            reinterpret_cast<const char*>(lK) + krow * 256 + (dbyte ^ ((krow & 7) << 4)));
        s[nf] = __builtin_amdgcn_mfma_f32_16x16x32_bf16(qf[kk], kf, s[nf], 0, 0, 0);
      }
    }

    // scale (log2 domain) + causal mask + row stats
    float rmax[4];
#pragma unroll
    for (int r = 0; r < 4; ++r) rmax[r] = -INFINITY;
#pragma unroll
    for (int nf = 0; nf < 4; ++nf) {
      int col = kt * 64 + nf * 16 + lc;
#pragma unroll
      for (int r = 0; r < 4; ++r) {
        int row = q0 + wv * 16 + lg * 4 + r;
        float sv = s[nf][r] * scaleL;
        if (col > row) sv = -INFINITY;
        s[nf][r] = sv;
        rmax[r] = fmaxf(rmax[r], sv);
      }
    }
#pragma unroll
    for (int mk = 1; mk < 16; mk <<= 1)
#pragma unroll
      for (int r = 0; r < 4; ++r)
        rmax[r] = fmaxf(rmax[r], __shfl_xor(rmax[r], mk));

    // defer-max: only rescale when the max grew by > 11.5 (log2) = e^8
    int need = 0;
#pragma unroll
    for (int r = 0; r < 4; ++r) need |= (rmax[r] > mrow[r] + 11.5f) ? 1 : 0;
    if (__any(need)) {
      float corr[4];
#pragma unroll
      for (int r = 0; r < 4; ++r) {
        float mnew = fmaxf(mrow[r], rmax[r]);
        corr[r] = exp2f(mrow[r] - mnew);
        mrow[r] = mnew;
        lrow[r] *= corr[r];
      }
#pragma unroll
      for (int dc = 0; dc < 8; ++dc)
#pragma unroll
        for (int r = 0; r < 4; ++r) oacc[dc][r] *= corr[r];
    }

    // P = 2^(s - m) -> lP (per-wave, padded)
#pragma unroll
    for (int nf = 0; nf < 4; ++nf) {
#pragma unroll
      for (int r = 0; r < 4; ++r) {
        float p = exp2f(s[nf][r] - mrow[r]);
        lrow[r] += p;
        lP[wv][(lg * 4 + r) * 72 + nf * 16 + lc] = f2b(p);
      }
    }
    bf16x8 pa[2];
#pragma unroll
    for (int kk = 0; kk < 2; ++kk)
      pa[kk] = *reinterpret_cast<const bf16x8*>(&lP[wv][lc * 72 + kk * 32 + lg * 8]);
#pragma unroll
    for (int dc = 0; dc < 8; ++dc) {
#pragma unroll
      for (int kk = 0; kk < 2; ++kk) {
        int vrow = dc * 16 + lc;
        int off = (kk * 64 + lg * 16) ^ ((vrow & 7) << 4);
        bf16x8 vf = *reinterpret_cast<const bf16x8*>(
            reinterpret_cast<const char*>(lVt) + vrow * 128 + off);
        oacc[dc] = __builtin_amdgcn_mfma_f32_16x16x32_bf16(pa[kk], vf, oacc[dc], 0, 0, 0);
      }
    }
  }

#pragma unroll
  for (int mk = 1; mk < 16; mk <<= 1)
#pragma unroll
    for (int r = 0; r < 4; ++r) lrow[r] += __shfl_xor(lrow[r], mk);

  const int b = bh >> 4, hh = bh & 15;
#pragma unroll
  for (int dc = 0; dc < 8; ++dc)
#pragma unroll
    for (int r = 0; r < 4; ++r) {
      int tt = q0 + wv * 16 + lg * 4 + r;
      int d = dc * 16 + lc;
      float o = oacc[dc][r] / lrow[r];
      outg[(size_t)(b * T + tt) * DM + hh * HD + d] = f2b(o);
    }
}

// ---------------- launch ----------------

extern "C" void kernel_launch(void* const* d_in, const int* in_sizes, int n_in,
                              void* d_out, int out_size, void* d_ws, size_t ws_size,
                              hipStream_t stream) {
  const float* x      = (const float*)d_in[0];
  const float* w_qkv  = (const float*)d_in[1];
  const float* w_proj = (const float*)d_in[2];
  const float* w_ff1  = (const float*)d_in[3];
  const float* b_ff1  = (const float*)d_in[4];
  const float* w_ff2  = (const float*)d_in[5];
  const float* b_ff2  = (const float*)d_in[6];
  float* out = (float*)d_out;

  u16* ws = (u16*)d_ws;
  size_t o = 0;
  u16* x_bf      = ws + o; o += (size_t)M * DM;
  u16* wqkv_t    = ws + o; o += (size_t)NQKV * DM;
  u16* wproj_t   = ws + o; o += (size_t)DM * DM;
  u16* wff1_t    = ws + o; o += (size_t)FF * DM;
  u16* wff2_t    = ws + o; o += (size_t)DM * FF;
  u16* attn_proj = ws + o; o += (size_t)M * DM;
  u16* qbuf      = ws + o;                    // q,k,vt,attn_out contiguous
  u16* kbuf      = qbuf + (size_t)M * DM;
  u16* vtbuf     = kbuf + (size_t)M * DM;     // V^T: [B][H][HD][T]
  u16* attn_out  = vtbuf + (size_t)M * DM;
  u16* hbuf      = qbuf;                      // aliases q|k|vt|attn_out = M*FF elems

  // conversions
  cvt_f32_to_bf16<<<(M * DM / 4 + 255) / 256, 256, 0, stream>>>(x, x_bf, M * DM / 4);
  transpose_cvt<<<dim3(NQKV / 32, DM / 32), 256, 0, stream>>>(w_qkv, wqkv_t, DM, NQKV);
  transpose_cvt<<<dim3(DM / 32, DM / 32), 256, 0, stream>>>(w_proj, wproj_t, DM, DM);
  transpose_cvt<<<dim3(FF / 32, DM / 32), 256, 0, stream>>>(w_ff1, wff1_t, DM, FF);
  transpose_cvt<<<dim3(DM / 32, FF / 32), 256, 0, stream>>>(w_ff2, wff2_t, FF, DM);

  // q,k projection (scatter into q/k): M=4096 x N=4096, grid 32x16=512
  gemm_bf16<0><<<512, 512, 0, stream>>>(
      x_bf, wqkv_t, 4096, DM, 32, qbuf, nullptr, nullptr, nullptr, nullptr);

  // V^T = Wv^T X^T: A = V-rows of wqkv_t [2048][2048], Bt = x_bf; M=2048 x N=4096, grid 32x8=256
  gemm_bf16<4><<<256, 512, 0, stream>>>(
      wqkv_t + (size_t)4096 * DM, x_bf, M, DM, 32, vtbuf, nullptr, nullptr, nullptr, nullptr);

  // causal flash attention
  attn_fwd<<<dim3(T / 64, BB * NH), 256, 0, stream>>>(qbuf, kbuf, vtbuf, attn_out);

  // output projection: 4096 x 2048, grid 16x16=256
  gemm_bf16<1><<<256, 512, 0, stream>>>(
      attn_out, wproj_t, DM, DM, 16, attn_proj, nullptr, nullptr, nullptr, nullptr);

  // FF1 + GELU: 4096 x 8192, grid 64x16=1024
  gemm_bf16<2><<<1024, 512, 0, stream>>>(
      x_bf, wff1_t, FF, DM, 64, hbuf, nullptr, b_ff1, nullptr, nullptr);

  // FF2 + bias + residuals -> f32 out: 4096 x 2048 (K=8192), grid 16x16=256
  gemm_bf16<3><<<256, 512, 0, stream>>>(
      hbuf, wff2_t, DM, FF, 16, nullptr, out, b_ff2, x, attn_proj);
}

// Round 6
// 676.940 us; speedup vs baseline: 1.3593x; 1.0209x over previous
//
#include <hip/hip_runtime.h>
#include <hip/hip_bf16.h>
#include <cmath>

typedef __bf16 bf16x8 __attribute__((ext_vector_type(8)));
typedef float f32x4 __attribute__((ext_vector_type(4)));
typedef unsigned short u16;
typedef unsigned int u32;

#define DEV __device__ __forceinline__

static constexpr int BB = 2;
static constexpr int T = 2048;
static constexpr int DM = 2048;
static constexpr int NH = 16;
static constexpr int HD = 128;
static constexpr int FF = 8192;
static constexpr int M = BB * T;      // 4096
static constexpr int NQKV = 3 * DM;   // 6144

DEV u16 f2b(float f) {
  u32 u = __builtin_bit_cast(u32, f);
  u = (u + 0x7FFFu + ((u >> 16) & 1u)) >> 16;
  return (u16)u;
}
DEV float b2f(u16 h) {
  u32 u = ((u32)h) << 16;
  return __builtin_bit_cast(float, u);
}

// async global->LDS, 16B per lane; LDS dest = wave-uniform base + lane*16
DEV void gload16(const u16* g, const u16* l) {
  __builtin_amdgcn_global_load_lds(
      (const __attribute__((address_space(1))) void*)(uintptr_t)g,
      (__attribute__((address_space(3))) void*)(unsigned)(uintptr_t)l,
      16, 0, 0);
}

// ---------------- conversions ----------------

__global__ void cvt_f32_to_bf16(const float* __restrict__ in, u16* __restrict__ out, int n4) {
  int i = blockIdx.x * blockDim.x + threadIdx.x;
  if (i >= n4) return;
  float4 v = reinterpret_cast<const float4*>(in)[i];
  ushort4 o;
  o.x = f2b(v.x); o.y = f2b(v.y); o.z = f2b(v.z); o.w = f2b(v.w);
  reinterpret_cast<ushort4*>(out)[i] = o;
}

// W [K][N] f32  ->  Wt [N][K] bf16
__global__ void transpose_cvt(const float* __restrict__ W, u16* __restrict__ Wt, int K, int N) {
  __shared__ float tile[32][33];
  int nb = blockIdx.x * 32, kb = blockIdx.y * 32;
  int tx = threadIdx.x & 31, ty = threadIdx.x >> 5;  // ty 0..7
#pragma unroll
  for (int r = 0; r < 32; r += 8)
    tile[ty + r][tx] = W[(size_t)(kb + ty + r) * N + nb + tx];
  __syncthreads();
#pragma unroll
  for (int r = 0; r < 32; r += 8)
    Wt[(size_t)(nb + ty + r) * K + kb + tx] = f2b(tile[tx][ty + r]);
}

// ---------------- GEMM ----------------
// C[M][N] = A[M][K] * Bt[N][K]^T, bf16 inputs, f32 accum.
// 256x128 tile, 8 waves (4m x 2n), BK=32. 3-buffer LDS pipeline with counted
// vmcnt(3) + raw s_barrier (no vmcnt(0) drain). Bijective XCD swizzle.
// LDS bank-swizzle: 64B rows would give 8-way ds_read_b128 conflicts (row
// stride = 16 banks); XOR byte-bits 4-5 with row-bits 1-2. Linear LDS dest
// (global_load_lds) + pre-swizzled SOURCE k-chunk + swizzled read col
// (both sides same involution; read col is a per-lane constant).
// EPI 0: scatter qk -> q/k (B,H,T,hd) bf16
// EPI 1: plain bf16 out
// EPI 2: bias + tanh-GELU, bf16 out
// EPI 3: bias + resid_f32 + resid_bf, f32 out
// EPI 4: V^T scatter: out[((b*NH+h)*HD+d)*T + t]
template <int EPI>
__global__ __launch_bounds__(512, 4) void gemm_bf16(
    const u16* __restrict__ A, const u16* __restrict__ Bt, int Ndim, int K, int gx,
    u16* __restrict__ out_bf, float* __restrict__ out_f32,
    const float* __restrict__ bias,
    const float* __restrict__ resid_f32, const u16* __restrict__ resid_bf) {
  __shared__ __align__(16) u16 lds[3 * (256 + 128) * 32];  // 72 KB
  const int t = threadIdx.x;
  // XCD-bijective swizzle: consecutive wg on one XCD share A-panels
  const int nwg = gridDim.x, cpx = nwg >> 3;
  const int wg = (blockIdx.x & 7) * cpx + (blockIdx.x >> 3);
  const int m0 = (wg / gx) * 256, n0 = (wg % gx) * 128;
  const int wave = t >> 6, lane = t & 63;
  const int wm = wave >> 1, wn = wave & 1;     // 4 x 2 wave grid, 64x64 each
  const int lr = lane & 15, lk = lane >> 4;

  // rotating buffers: each = A[256][32] + B[128][32]
  u16* cA = lds;                   u16* cB = lds + 8192;
  u16* nA = lds + 12288;           u16* nB = lds + 12288 + 8192;
  u16* sA = lds + 2 * 12288;       u16* sB = lds + 2 * 12288 + 8192;

  // staging: row = wave*16 + (lane>>2); source k-chunk pre-swizzled so that
  // LDS cell (row, c) holds k-chunk c ^ ((row>>1)&3)   [(row>>1)&3 = (lane>>3)&3]
  const int sk = (((lane & 3) ^ ((lane >> 3) & 3))) * 8;
  const u16* gA0 = &A[(size_t)(m0 + wave * 16 + (lane >> 2)) * K + sk];
  const u16* gA1 = gA0 + (size_t)128 * K;
  const u16* gB0 = &Bt[(size_t)(n0 + wave * 16 + (lane >> 2)) * K + sk];

  const int wbase = wave * 512;  // wave's 16-row chunk (16*32 elems)

  auto stage = [&](u16* dA, u16* dB) {
    gload16(gA0, dA + wbase);
    gload16(gA1, dA + 4096 + wbase);
    gload16(gB0, dB + wbase);
    gA0 += 32; gA1 += 32; gB0 += 32;
  };

  const int NT = K >> 5;

  stage(cA, cB);
  stage(nA, nB);
  __builtin_amdgcn_sched_barrier(0);
  asm volatile("s_waitcnt vmcnt(3)" ::: "memory");
  __builtin_amdgcn_s_barrier();
  __builtin_amdgcn_sched_barrier(0);

  f32x4 acc[4][4] = {};

  // read col swizzle: want k-chunk lk from row wr -> cell lk ^ ((wr>>1)&3);
  // (wr>>1)&3 == (lr>>1)&3 for all fragment rows (wm*64, i*16 are mult of 8)
  const int rcol = (lk ^ ((lr >> 1) & 3)) * 8;

  for (int kt = 0; kt < NT; ++kt) {
    if (kt + 2 < NT) stage(sA, sB);
    bf16x8 af[4], bfr[4];
#pragma unroll
    for (int i = 0; i < 4; ++i) {
      af[i]  = *reinterpret_cast<const bf16x8*>(&cA[(wm * 64 + i * 16 + lr) * 32 + rcol]);
      bfr[i] = *reinterpret_cast<const bf16x8*>(&cB[(wn * 64 + i * 16 + lr) * 32 + rcol]);
    }
#pragma unroll
    for (int i = 0; i < 4; ++i)
#pragma unroll
      for (int j = 0; j < 4; ++j)
        acc[i][j] = __builtin_amdgcn_mfma_f32_16x16x32_bf16(af[i], bfr[j], acc[i][j], 0, 0, 0);
    if (kt + 1 < NT) {
      __builtin_amdgcn_sched_barrier(0);
      if (kt + 2 < NT) asm volatile("s_waitcnt vmcnt(3)" ::: "memory");
      else             asm volatile("s_waitcnt vmcnt(0)" ::: "memory");
      __builtin_amdgcn_s_barrier();
      __builtin_amdgcn_sched_barrier(0);
      u16* tA = cA; u16* tB = cB;
      cA = nA; cB = nB; nA = sA; nB = sB; sA = tA; sB = tB;
    }
  }

#pragma unroll
  for (int i = 0; i < 4; ++i) {
#pragma unroll
    for (int j = 0; j < 4; ++j) {
#pragma unroll
      for (int r = 0; r < 4; ++r) {
        int gr = m0 + wm * 64 + i * 16 + (lane >> 4) * 4 + r;
        int gc = n0 + wn * 64 + j * 16 + (lane & 15);
        float v = acc[i][j][r];
        if constexpr (EPI == 0) {
          int part = gc >> 11, cc = gc & 2047;
          int head = cc >> 7, d = cc & 127;
          int b = gr >> 11, tt = gr & 2047;
          out_bf[(size_t)part * M * DM + (((size_t)(b * NH + head) * T + tt) * HD + d)] = f2b(v);
        } else if constexpr (EPI == 1) {
          out_bf[(size_t)gr * Ndim + gc] = f2b(v);
        } else if constexpr (EPI == 2) {
          v += bias[gc];
          // tanh-form GELU; exp2f -> native v_exp_f32
          float u = v * (v * v * 0.044715f + 1.0f) * 0.7978845608028654f;
          float e = exp2f(u * 2.885390081777927f);  // e^(2u)
          float th = 1.0f - 2.0f / (e + 1.0f);
          v = 0.5f * v * (1.0f + th);
          out_bf[(size_t)gr * Ndim + gc] = f2b(v);
        } else if constexpr (EPI == 3) {
          v += bias[gc] + resid_f32[(size_t)gr * Ndim + gc] + b2f(resid_bf[(size_t)gr * Ndim + gc]);
          out_f32[(size_t)gr * Ndim + gc] = v;
        } else {  // EPI 4: V^T
          int hh = gr >> 7, d = gr & 127;
          int b = gc >> 11, tt = gc & 2047;
          out_bf[((size_t)(b * NH + hh) * HD + d) * T + tt] = f2b(v);
        }
      }
    }
  }
}

// ---------------- attention ----------------
// grid (T/64, B*NH); 4 waves, each owns 16 q-rows; KV tiles of 64; causal flash.
// Longest-first dispatch (qi reversed); defer-max rescale (T13, log2 THR=11.5).
__global__ __launch_bounds__(256) void attn_fwd(
    const u16* __restrict__ qg, const u16* __restrict__ kg,
    const u16* __restrict__ vt, u16* __restrict__ outg) {
  __shared__ __align__(16) u16 lK[64 * 128];    // 16 KB
  __shared__ __align__(16) u16 lVt[128 * 64];   // 16 KB
  __shared__ __align__(16) u16 lP[4][16 * 72];
  const int t = threadIdx.x;
  const int qi = gridDim.x - 1 - blockIdx.x;   // longest blocks first
  const int bh = blockIdx.y;
  const int wv = t >> 6, lane = t & 63;
  const int lc = lane & 15, lg = lane >> 4;
  const size_t base = (size_t)bh * T * HD;   // q, k: [T][HD]
  const size_t vbase = (size_t)bh * HD * T;  // vt:   [HD][T]
  const int q0 = qi * 64;

  bf16x8 qf[4];
#pragma unroll
  for (int kk = 0; kk < 4; ++kk)
    qf[kk] = *reinterpret_cast<const bf16x8*>(
        &qg[base + (size_t)(q0 + wv * 16 + lc) * HD + kk * 32 + lg * 8]);

  f32x4 oacc[8] = {};
  float mrow[4], lrow[4];
#pragma unroll
  for (int r = 0; r < 4; ++r) { mrow[r] = -INFINITY; lrow[r] = 0.f; }

  // 1/sqrt(128) * log2(e): softmax in base 2 (v_exp_f32 is native 2^x)
  const float scaleL = 0.08838834764831845f * 1.4426950408889634f;
  const int ntiles = qi + 1;
  for (int kt = 0; kt < ntiles; ++kt) {
    __syncthreads();
    // K: 4 gload calls, rows 256B; source pre-swizzled by ((row&7)<<4)
#pragma unroll
    for (int h = 0; h < 4; ++h) {
      int row = h * 16 + wv * 4 + (lane >> 4);
      int sb = ((lane & 15) * 16) ^ ((row & 7) << 4);
      gload16(&kg[base + (size_t)(kt * 64 + row) * HD + (sb >> 1)],
              (const u16*)((const char*)lK + (h * 256 + wv * 64) * 16));
    }
    // V^T: 4 gload calls, rows 128B
#pragma unroll
    for (int h = 0; h < 4; ++h) {
      int row = h * 32 + wv * 8 + (lane >> 3);
      int sb = ((lane & 7) * 16) ^ ((row & 7) << 4);
      gload16(&vt[vbase + (size_t)row * T + kt * 64 + (sb >> 1)],
              (const u16*)((const char*)lVt + (h * 256 + wv * 64) * 16));
    }
    __syncthreads();

    // S = Q K^T
    f32x4 s[4] = {};
#pragma unroll
    for (int nf = 0; nf < 4; ++nf) {
      int krow = nf * 16 + lc;
#pragma unroll
      for (int kk = 0; kk < 4; ++kk) {
        int dbyte = kk * 64 + lg * 16;
        bf16x8 kf = *reinterpret_cast<const bf16x8*>(
            reinterpret_cast<const char*>(lK) + krow * 256 + (dbyte ^ ((krow & 7) << 4)));
        s[nf] = __builtin_amdgcn_mfma_f32_16x16x32_bf16(qf[kk], kf, s[nf], 0, 0, 0);
      }
    }

    // scale (log2 domain) + causal mask + row stats
    float rmax[4];
#pragma unroll
    for (int r = 0; r < 4; ++r) rmax[r] = -INFINITY;
#pragma unroll
    for (int nf = 0; nf < 4; ++nf) {
      int col = kt * 64 + nf * 16 + lc;
#pragma unroll
      for (int r = 0; r < 4; ++r) {
        int row = q0 + wv * 16 + lg * 4 + r;
        float sv = s[nf][r] * scaleL;
        if (col > row) sv = -INFINITY;
        s[nf][r] = sv;
        rmax[r] = fmaxf(rmax[r], sv);
      }
    }
#pragma unroll
    for (int mk = 1; mk < 16; mk <<= 1)
#pragma unroll
      for (int r = 0; r < 4; ++r)
        rmax[r] = fmaxf(rmax[r], __shfl_xor(rmax[r], mk));

    // defer-max: only rescale when the max grew by > 11.5 (log2) = e^8
    int need = 0;
#pragma unroll
    for (int r = 0; r < 4; ++r) need |= (rmax[r] > mrow[r] + 11.5f) ? 1 : 0;
    if (__any(need)) {
      float corr[4];
#pragma unroll
      for (int r = 0; r < 4; ++r) {
        float mnew = fmaxf(mrow[r], rmax[r]);
        corr[r] = exp2f(mrow[r] - mnew);
        mrow[r] = mnew;
        lrow[r] *= corr[r];
      }
#pragma unroll
      for (int dc = 0; dc < 8; ++dc)
#pragma unroll
        for (int r = 0; r < 4; ++r) oacc[dc][r] *= corr[r];
    }

    // P = 2^(s - m) -> lP (per-wave, padded)
#pragma unroll
    for (int nf = 0; nf < 4; ++nf) {
#pragma unroll
      for (int r = 0; r < 4; ++r) {
        float p = exp2f(s[nf][r] - mrow[r]);
        lrow[r] += p;
        lP[wv][(lg * 4 + r) * 72 + nf * 16 + lc] = f2b(p);
      }
    }
    bf16x8 pa[2];
#pragma unroll
    for (int kk = 0; kk < 2; ++kk)
      pa[kk] = *reinterpret_cast<const bf16x8*>(&lP[wv][lc * 72 + kk * 32 + lg * 8]);
#pragma unroll
    for (int dc = 0; dc < 8; ++dc) {
#pragma unroll
      for (int kk = 0; kk < 2; ++kk) {
        int vrow = dc * 16 + lc;
        int off = (kk * 64 + lg * 16) ^ ((vrow & 7) << 4);
        bf16x8 vf = *reinterpret_cast<const bf16x8*>(
            reinterpret_cast<const char*>(lVt) + vrow * 128 + off);
        oacc[dc] = __builtin_amdgcn_mfma_f32_16x16x32_bf16(pa[kk], vf, oacc[dc], 0, 0, 0);
      }
    }
  }

#pragma unroll
  for (int mk = 1; mk < 16; mk <<= 1)
#pragma unroll
    for (int r = 0; r < 4; ++r) lrow[r] += __shfl_xor(lrow[r], mk);

  const int b = bh >> 4, hh = bh & 15;
#pragma unroll
  for (int dc = 0; dc < 8; ++dc)
#pragma unroll
    for (int r = 0; r < 4; ++r) {
      int tt = q0 + wv * 16 + lg * 4 + r;
      int d = dc * 16 + lc;
      float o = oacc[dc][r] / lrow[r];
      outg[(size_t)(b * T + tt) * DM + hh * HD + d] = f2b(o);
    }
}

// ---------------- launch ----------------

extern "C" void kernel_launch(void* const* d_in, const int* in_sizes, int n_in,
                              void* d_out, int out_size, void* d_ws, size_t ws_size,
                              hipStream_t stream) {
  const float* x      = (const float*)d_in[0];
  const float* w_qkv  = (const float*)d_in[1];
  const float* w_proj = (const float*)d_in[2];
  const float* w_ff1  = (const float*)d_in[3];
  const float* b_ff1  = (const float*)d_in[4];
  const float* w_ff2  = (const float*)d_in[5];
  const float* b_ff2  = (const float*)d_in[6];
  float* out = (float*)d_out;

  u16* ws = (u16*)d_ws;
  size_t o = 0;
  u16* x_bf      = ws + o; o += (size_t)M * DM;
  u16* wqkv_t    = ws + o; o += (size_t)NQKV * DM;
  u16* wproj_t   = ws + o; o += (size_t)DM * DM;
  u16* wff1_t    = ws + o; o += (size_t)FF * DM;
  u16* wff2_t    = ws + o; o += (size_t)DM * FF;
  u16* attn_proj = ws + o; o += (size_t)M * DM;
  u16* qbuf      = ws + o;                    // q,k,vt,attn_out contiguous
  u16* kbuf      = qbuf + (size_t)M * DM;
  u16* vtbuf     = kbuf + (size_t)M * DM;     // V^T: [B][H][HD][T]
  u16* attn_out  = vtbuf + (size_t)M * DM;
  u16* hbuf      = qbuf;                      // aliases q|k|vt|attn_out = M*FF elems

  // conversions
  cvt_f32_to_bf16<<<(M * DM / 4 + 255) / 256, 256, 0, stream>>>(x, x_bf, M * DM / 4);
  transpose_cvt<<<dim3(NQKV / 32, DM / 32), 256, 0, stream>>>(w_qkv, wqkv_t, DM, NQKV);
  transpose_cvt<<<dim3(DM / 32, DM / 32), 256, 0, stream>>>(w_proj, wproj_t, DM, DM);
  transpose_cvt<<<dim3(FF / 32, DM / 32), 256, 0, stream>>>(w_ff1, wff1_t, DM, FF);
  transpose_cvt<<<dim3(DM / 32, FF / 32), 256, 0, stream>>>(w_ff2, wff2_t, FF, DM);

  // q,k projection (scatter into q/k): M=4096 x N=4096, grid 32x16=512
  gemm_bf16<0><<<512, 512, 0, stream>>>(
      x_bf, wqkv_t, 4096, DM, 32, qbuf, nullptr, nullptr, nullptr, nullptr);

  // V^T = Wv^T X^T: A = V-rows of wqkv_t [2048][2048], Bt = x_bf; M=2048 x N=4096, grid 32x8=256
  gemm_bf16<4><<<256, 512, 0, stream>>>(
      wqkv_t + (size_t)4096 * DM, x_bf, M, DM, 32, vtbuf, nullptr, nullptr, nullptr, nullptr);

  // causal flash attention
  attn_fwd<<<dim3(T / 64, BB * NH), 256, 0, stream>>>(qbuf, kbuf, vtbuf, attn_out);

  // output projection: 4096 x 2048, grid 16x16=256
  gemm_bf16<1><<<256, 512, 0, stream>>>(
      attn_out, wproj_t, DM, DM, 16, attn_proj, nullptr, nullptr, nullptr, nullptr);

  // FF1 + GELU: 4096 x 8192, grid 64x16=1024
  gemm_bf16<2><<<1024, 512, 0, stream>>>(
      x_bf, wff1_t, FF, DM, 64, hbuf, nullptr, b_ff1, nullptr, nullptr);

  // FF2 + bias + residuals -> f32 out: 4096 x 2048 (K=8192), grid 16x16=256
  gemm_bf16<3><<<256, 512, 0, stream>>>(
      hbuf, wff2_t, DM, FF, 16, nullptr, out, b_ff2, x, attn_proj);
}

// Round 7
// 669.966 us; speedup vs baseline: 1.3734x; 1.0104x over previous
//
#include <hip/hip_runtime.h>
#include <hip/hip_bf16.h>
#include <cmath>

typedef __bf16 bf16x8 __attribute__((ext_vector_type(8)));
typedef float f32x4 __attribute__((ext_vector_type(4)));
typedef unsigned short u16;
typedef unsigned int u32;

#define DEV __device__ __forceinline__

static constexpr int BB = 2;
static constexpr int T = 2048;
static constexpr int DM = 2048;
static constexpr int NH = 16;
static constexpr int HD = 128;
static constexpr int FF = 8192;
static constexpr int M = BB * T;      // 4096
static constexpr int NQKV = 3 * DM;   // 6144

DEV u16 f2b(float f) {
  u32 u = __builtin_bit_cast(u32, f);
  u = (u + 0x7FFFu + ((u >> 16) & 1u)) >> 16;
  return (u16)u;
}
DEV float b2f(u16 h) {
  u32 u = ((u32)h) << 16;
  return __builtin_bit_cast(float, u);
}

// async global->LDS, 16B per lane; LDS dest = wave-uniform base + lane*16
DEV void gload16(const u16* g, const u16* l) {
  __builtin_amdgcn_global_load_lds(
      (const __attribute__((address_space(1))) void*)(uintptr_t)g,
      (__attribute__((address_space(3))) void*)(unsigned)(uintptr_t)l,
      16, 0, 0);
}

// ---------------- conversions ----------------

__global__ void cvt_f32_to_bf16(const float* __restrict__ in, u16* __restrict__ out, int n4) {
  int i = blockIdx.x * blockDim.x + threadIdx.x;
  if (i >= n4) return;
  float4 v = reinterpret_cast<const float4*>(in)[i];
  ushort4 o;
  o.x = f2b(v.x); o.y = f2b(v.y); o.z = f2b(v.z); o.w = f2b(v.w);
  reinterpret_cast<ushort4*>(out)[i] = o;
}

// W [K][N] f32  ->  Wt [N][K] bf16
__global__ void transpose_cvt(const float* __restrict__ W, u16* __restrict__ Wt, int K, int N) {
  __shared__ float tile[32][33];
  int nb = blockIdx.x * 32, kb = blockIdx.y * 32;
  int tx = threadIdx.x & 31, ty = threadIdx.x >> 5;  // ty 0..7
#pragma unroll
  for (int r = 0; r < 32; r += 8)
    tile[ty + r][tx] = W[(size_t)(kb + ty + r) * N + nb + tx];
  __syncthreads();
#pragma unroll
  for (int r = 0; r < 32; r += 8)
    Wt[(size_t)(nb + ty + r) * K + kb + tx] = f2b(tile[tx][ty + r]);
}

// ---------------- GEMM ----------------
// C[M][N] = A[M][K] * Bt[N][K]^T, bf16 inputs, f32 accum.
// BM=256, BN=64*NWN. 2*NWN waves, each owns a 128x64 output tile (8x4 frags,
// 32 MFMA/K-step — reuse ratio 42.7 FLOP/LDS-elem vs 32 for 64x64).
// 3-buffer LDS pipeline, counted vmcnt (never 0 in steady state), raw
// s_barrier. Bank swizzle: XOR byte-bits 4-5 with row-bits 1-2 (linear LDS
// dest + pre-swizzled source + per-lane-constant read col). XCD-bijective
// block swizzle.
// EPI 0: scatter qk -> q/k (B,H,T,hd) bf16
// EPI 1: plain bf16 out
// EPI 2: bias + tanh-GELU, bf16 out
// EPI 3: bias + resid_f32 + resid_bf, f32 out
// EPI 4: V^T scatter: out[((b*NH+h)*HD+d)*T + t]
template <int EPI, int NWN>
__global__ __launch_bounds__(NWN * 128, 2) void gemm_bf16(
    const u16* __restrict__ A, const u16* __restrict__ Bt, int Ndim, int K, int gx,
    u16* __restrict__ out_bf, float* __restrict__ out_f32,
    const float* __restrict__ bias,
    const float* __restrict__ resid_f32, const u16* __restrict__ resid_bf) {
  constexpr int BN = NWN * 64;          // 256 or 128
  constexpr int NW = NWN * 2;           // waves per block
  constexpr int AG = 256 / (16 * NW);   // A gloads per wave per stage
  constexpr int BG = BN / (16 * NW);    // B gloads per wave per stage
  constexpr int L = AG + BG;            // loads in flight per staged tile
  constexpr int BUF = (256 + BN) * 32;  // elems per buffer
  __shared__ __align__(16) u16 lds[3 * BUF];
  const int t = threadIdx.x;
  // XCD-bijective swizzle (all grids % 8 == 0)
  const int nwg = gridDim.x, cpx = nwg >> 3;
  const int wg = (blockIdx.x & 7) * cpx + (blockIdx.x >> 3);
  const int m0 = (wg / gx) * 256, n0 = (wg % gx) * BN;
  const int wave = t >> 6, lane = t & 63;
  const int wm = wave & 1, wn = wave >> 1;  // wave tile: rows wm*128, cols wn*64
  const int lr = lane & 15, lk = lane >> 4;

  u16* cA = lds;             u16* cB = lds + 8192;
  u16* nA = lds + BUF;       u16* nB = lds + BUF + 8192;
  u16* sA = lds + 2 * BUF;   u16* sB = lds + 2 * BUF + 8192;

  // staging: row covered = base + g*16 + (lane>>2); source k-chunk pre-swizzled
  // so LDS cell (row, c) holds chunk c ^ ((row>>1)&3); (row>>1)&3 == (lane>>3)&3
  const int sk = ((lane & 3) ^ ((lane >> 3) & 3)) * 8;
  const u16* gA[AG];
  const u16* gB[BG];
#pragma unroll
  for (int g = 0; g < AG; ++g)
    gA[g] = &A[(size_t)(m0 + wave * (16 * AG) + g * 16 + (lane >> 2)) * K + sk];
#pragma unroll
  for (int g = 0; g < BG; ++g)
    gB[g] = &Bt[(size_t)(n0 + wave * (16 * BG) + g * 16 + (lane >> 2)) * K + sk];

  auto stage = [&](u16* dA, u16* dB) {
#pragma unroll
    for (int g = 0; g < AG; ++g) { gload16(gA[g], dA + wave * (AG * 512) + g * 512); gA[g] += 32; }
#pragma unroll
    for (int g = 0; g < BG; ++g) { gload16(gB[g], dB + wave * (BG * 512) + g * 512); gB[g] += 32; }
  };

  auto waitL = [&]() {
    if constexpr (L == 4) asm volatile("s_waitcnt vmcnt(4)" ::: "memory");
    else                  asm volatile("s_waitcnt vmcnt(6)" ::: "memory");
  };

  const int NT = K >> 5;

  stage(cA, cB);
  stage(nA, nB);
  __builtin_amdgcn_sched_barrier(0);
  waitL();
  __builtin_amdgcn_s_barrier();
  __builtin_amdgcn_sched_barrier(0);

  f32x4 acc[8][4] = {};

  // read col: want k-chunk lk from row -> cell lk ^ ((row>>1)&3); row parity == lr's
  const int rcol = (lk ^ ((lr >> 1) & 3)) * 8;

  for (int kt = 0; kt < NT; ++kt) {
    if (kt + 2 < NT) stage(sA, sB);
    bf16x8 af[8], bfr[4];
#pragma unroll
    for (int i = 0; i < 8; ++i)
      af[i] = *reinterpret_cast<const bf16x8*>(&cA[(wm * 128 + i * 16 + lr) * 32 + rcol]);
#pragma unroll
    for (int j = 0; j < 4; ++j)
      bfr[j] = *reinterpret_cast<const bf16x8*>(&cB[(wn * 64 + j * 16 + lr) * 32 + rcol]);
#pragma unroll
    for (int i = 0; i < 8; ++i)
#pragma unroll
      for (int j = 0; j < 4; ++j)
        acc[i][j] = __builtin_amdgcn_mfma_f32_16x16x32_bf16(af[i], bfr[j], acc[i][j], 0, 0, 0);
    if (kt + 1 < NT) {
      __builtin_amdgcn_sched_barrier(0);
      if (kt + 2 < NT) waitL();
      else             asm volatile("s_waitcnt vmcnt(0)" ::: "memory");
      __builtin_amdgcn_s_barrier();
      __builtin_amdgcn_sched_barrier(0);
      u16* tA = cA; u16* tB = cB;
      cA = nA; cB = nB; nA = sA; nB = sB; sA = tA; sB = tB;
    }
  }

#pragma unroll
  for (int i = 0; i < 8; ++i) {
#pragma unroll
    for (int j = 0; j < 4; ++j) {
#pragma unroll
      for (int r = 0; r < 4; ++r) {
        int gr = m0 + wm * 128 + i * 16 + (lane >> 4) * 4 + r;
        int gc = n0 + wn * 64 + j * 16 + (lane & 15);
        float v = acc[i][j][r];
        if constexpr (EPI == 0) {
          int part = gc >> 11, cc = gc & 2047;
          int head = cc >> 7, d = cc & 127;
          int b = gr >> 11, tt = gr & 2047;
          out_bf[(size_t)part * M * DM + (((size_t)(b * NH + head) * T + tt) * HD + d)] = f2b(v);
        } else if constexpr (EPI == 1) {
          out_bf[(size_t)gr * Ndim + gc] = f2b(v);
        } else if constexpr (EPI == 2) {
          v += bias[gc];
          // tanh-form GELU; exp2f -> native v_exp_f32
          float u = v * (v * v * 0.044715f + 1.0f) * 0.7978845608028654f;
          float e = exp2f(u * 2.885390081777927f);  // e^(2u)
          float th = 1.0f - 2.0f / (e + 1.0f);
          v = 0.5f * v * (1.0f + th);
          out_bf[(size_t)gr * Ndim + gc] = f2b(v);
        } else if constexpr (EPI == 3) {
          v += bias[gc] + resid_f32[(size_t)gr * Ndim + gc] + b2f(resid_bf[(size_t)gr * Ndim + gc]);
          out_f32[(size_t)gr * Ndim + gc] = v;
        } else {  // EPI 4: V^T
          int hh = gr >> 7, d = gr & 127;
          int b = gc >> 11, tt = gc & 2047;
          out_bf[((size_t)(b * NH + hh) * HD + d) * T + tt] = f2b(v);
        }
      }
    }
  }
}

// ---------------- attention ----------------
// grid (T/64, B*NH); 4 waves, each owns 16 q-rows; KV tiles of 64; causal flash.
// Longest-first dispatch (qi reversed); defer-max rescale (T13, log2 THR=11.5).
__global__ __launch_bounds__(256) void attn_fwd(
    const u16* __restrict__ qg, const u16* __restrict__ kg,
    const u16* __restrict__ vt, u16* __restrict__ outg) {
  __shared__ __align__(16) u16 lK[64 * 128];    // 16 KB
  __shared__ __align__(16) u16 lVt[128 * 64];   // 16 KB
  __shared__ __align__(16) u16 lP[4][16 * 72];
  const int t = threadIdx.x;
  const int qi = gridDim.x - 1 - blockIdx.x;   // longest blocks first
  const int bh = blockIdx.y;
  const int wv = t >> 6, lane = t & 63;
  const int lc = lane & 15, lg = lane >> 4;
  const size_t base = (size_t)bh * T * HD;   // q, k: [T][HD]
  const size_t vbase = (size_t)bh * HD * T;  // vt:   [HD][T]
  const int q0 = qi * 64;

  bf16x8 qf[4];
#pragma unroll
  for (int kk = 0; kk < 4; ++kk)
    qf[kk] = *reinterpret_cast<const bf16x8*>(
        &qg[base + (size_t)(q0 + wv * 16 + lc) * HD + kk * 32 + lg * 8]);

  f32x4 oacc[8] = {};
  float mrow[4], lrow[4];
#pragma unroll
  for (int r = 0; r < 4; ++r) { mrow[r] = -INFINITY; lrow[r] = 0.f; }

  // 1/sqrt(128) * log2(e): softmax in base 2 (v_exp_f32 is native 2^x)
  const float scaleL = 0.08838834764831845f * 1.4426950408889634f;
  const int ntiles = qi + 1;
  for (int kt = 0; kt < ntiles; ++kt) {
    __syncthreads();
    // K: 4 gload calls, rows 256B; source pre-swizzled by ((row&7)<<4)
#pragma unroll
    for (int h = 0; h < 4; ++h) {
      int row = h * 16 + wv * 4 + (lane >> 4);
      int sb = ((lane & 15) * 16) ^ ((row & 7) << 4);
      gload16(&kg[base + (size_t)(kt * 64 + row) * HD + (sb >> 1)],
              (const u16*)((const char*)lK + (h * 256 + wv * 64) * 16));
    }
    // V^T: 4 gload calls, rows 128B
#pragma unroll
    for (int h = 0; h < 4; ++h) {
      int row = h * 32 + wv * 8 + (lane >> 3);
      int sb = ((lane & 7) * 16) ^ ((row & 7) << 4);
      gload16(&vt[vbase + (size_t)row * T + kt * 64 + (sb >> 1)],
              (const u16*)((const char*)lVt + (h * 256 + wv * 64) * 16));
    }
    __syncthreads();

    // S = Q K^T
    f32x4 s[4] = {};
#pragma unroll
    for (int nf = 0; nf < 4; ++nf) {
      int krow = nf * 16 + lc;
#pragma unroll
      for (int kk = 0; kk < 4; ++kk) {
        int dbyte = kk * 64 + lg * 16;
        bf16x8 kf = *reinterpret_cast<const bf16x8*>(
            reinterpret_cast<const char*>(lK) + krow * 256 + (dbyte ^ ((krow & 7) << 4)));
        s[nf] = __builtin_amdgcn_mfma_f32_16x16x32_bf16(qf[kk], kf, s[nf], 0, 0, 0);
      }
    }

    // scale (log2 domain) + causal mask + row stats
    float rmax[4];
#pragma unroll
    for (int r = 0; r < 4; ++r) rmax[r] = -INFINITY;
#pragma unroll
    for (int nf = 0; nf < 4; ++nf) {
      int col = kt * 64 + nf * 16 + lc;
#pragma unroll
      for (int r = 0; r < 4; ++r) {
        int row = q0 + wv * 16 + lg * 4 + r;
        float sv = s[nf][r] * scaleL;
        if (col > row) sv = -INFINITY;
        s[nf][r] = sv;
        rmax[r] = fmaxf(rmax[r], sv);
      }
    }
#pragma unroll
    for (int mk = 1; mk < 16; mk <<= 1)
#pragma unroll
      for (int r = 0; r < 4; ++r)
        rmax[r] = fmaxf(rmax[r], __shfl_xor(rmax[r], mk));

    // defer-max: only rescale when the max grew by > 11.5 (log2) = e^8
    int need = 0;
#pragma unroll
    for (int r = 0; r < 4; ++r) need |= (rmax[r] > mrow[r] + 11.5f) ? 1 : 0;
    if (__any(need)) {
      float corr[4];
#pragma unroll
      for (int r = 0; r < 4; ++r) {
        float mnew = fmaxf(mrow[r], rmax[r]);
        corr[r] = exp2f(mrow[r] - mnew);
        mrow[r] = mnew;
        lrow[r] *= corr[r];
      }
#pragma unroll
      for (int dc = 0; dc < 8; ++dc)
#pragma unroll
        for (int r = 0; r < 4; ++r) oacc[dc][r] *= corr[r];
    }

    // P = 2^(s - m) -> lP (per-wave, padded)
#pragma unroll
    for (int nf = 0; nf < 4; ++nf) {
#pragma unroll
      for (int r = 0; r < 4; ++r) {
        float p = exp2f(s[nf][r] - mrow[r]);
        lrow[r] += p;
        lP[wv][(lg * 4 + r) * 72 + nf * 16 + lc] = f2b(p);
      }
    }
    bf16x8 pa[2];
#pragma unroll
    for (int kk = 0; kk < 2; ++kk)
      pa[kk] = *reinterpret_cast<const bf16x8*>(&lP[wv][lc * 72 + kk * 32 + lg * 8]);
#pragma unroll
    for (int dc = 0; dc < 8; ++dc) {
#pragma unroll
      for (int kk = 0; kk < 2; ++kk) {
        int vrow = dc * 16 + lc;
        int off = (kk * 64 + lg * 16) ^ ((vrow & 7) << 4);
        bf16x8 vf = *reinterpret_cast<const bf16x8*>(
            reinterpret_cast<const char*>(lVt) + vrow * 128 + off);
        oacc[dc] = __builtin_amdgcn_mfma_f32_16x16x32_bf16(pa[kk], vf, oacc[dc], 0, 0, 0);
      }
    }
  }

#pragma unroll
  for (int mk = 1; mk < 16; mk <<= 1)
#pragma unroll
    for (int r = 0; r < 4; ++r) lrow[r] += __shfl_xor(lrow[r], mk);

  const int b = bh >> 4, hh = bh & 15;
#pragma unroll
  for (int dc = 0; dc < 8; ++dc)
#pragma unroll
    for (int r = 0; r < 4; ++r) {
      int tt = q0 + wv * 16 + lg * 4 + r;
      int d = dc * 16 + lc;
      float o = oacc[dc][r] / lrow[r];
      outg[(size_t)(b * T + tt) * DM + hh * HD + d] = f2b(o);
    }
}

// ---------------- launch ----------------

extern "C" void kernel_launch(void* const* d_in, const int* in_sizes, int n_in,
                              void* d_out, int out_size, void* d_ws, size_t ws_size,
                              hipStream_t stream) {
  const float* x      = (const float*)d_in[0];
  const float* w_qkv  = (const float*)d_in[1];
  const float* w_proj = (const float*)d_in[2];
  const float* w_ff1  = (const float*)d_in[3];
  const float* b_ff1  = (const float*)d_in[4];
  const float* w_ff2  = (const float*)d_in[5];
  const float* b_ff2  = (const float*)d_in[6];
  float* out = (float*)d_out;

  u16* ws = (u16*)d_ws;
  size_t o = 0;
  u16* x_bf      = ws + o; o += (size_t)M * DM;
  u16* wqkv_t    = ws + o; o += (size_t)NQKV * DM;
  u16* wproj_t   = ws + o; o += (size_t)DM * DM;
  u16* wff1_t    = ws + o; o += (size_t)FF * DM;
  u16* wff2_t    = ws + o; o += (size_t)DM * FF;
  u16* attn_proj = ws + o; o += (size_t)M * DM;
  u16* qbuf      = ws + o;                    // q,k,vt,attn_out contiguous
  u16* kbuf      = qbuf + (size_t)M * DM;
  u16* vtbuf     = kbuf + (size_t)M * DM;     // V^T: [B][H][HD][T]
  u16* attn_out  = vtbuf + (size_t)M * DM;
  u16* hbuf      = qbuf;                      // aliases q|k|vt|attn_out = M*FF elems

  // conversions
  cvt_f32_to_bf16<<<(M * DM / 4 + 255) / 256, 256, 0, stream>>>(x, x_bf, M * DM / 4);
  transpose_cvt<<<dim3(NQKV / 32, DM / 32), 256, 0, stream>>>(w_qkv, wqkv_t, DM, NQKV);
  transpose_cvt<<<dim3(DM / 32, DM / 32), 256, 0, stream>>>(w_proj, wproj_t, DM, DM);
  transpose_cvt<<<dim3(FF / 32, DM / 32), 256, 0, stream>>>(w_ff1, wff1_t, DM, FF);
  transpose_cvt<<<dim3(DM / 32, FF / 32), 256, 0, stream>>>(w_ff2, wff2_t, FF, DM);

  // q,k projection (scatter into q/k): 4096x4096, 256x256 tiles -> grid 16x16=256
  gemm_bf16<0, 4><<<256, 512, 0, stream>>>(
      x_bf, wqkv_t, 4096, DM, 16, qbuf, nullptr, nullptr, nullptr, nullptr);

  // V^T = Wv^T X^T: 2048x4096, 256x128 tiles -> grid 8x32=256
  gemm_bf16<4, 2><<<256, 256, 0, stream>>>(
      wqkv_t + (size_t)4096 * DM, x_bf, M, DM, 32, vtbuf, nullptr, nullptr, nullptr, nullptr);

  // causal flash attention
  attn_fwd<<<dim3(T / 64, BB * NH), 256, 0, stream>>>(qbuf, kbuf, vtbuf, attn_out);

  // output projection: 4096x2048, 256x128 tiles -> grid 16x16=256
  gemm_bf16<1, 2><<<256, 256, 0, stream>>>(
      attn_out, wproj_t, DM, DM, 16, attn_proj, nullptr, nullptr, nullptr, nullptr);

  // FF1 + GELU: 4096x8192, 256x256 tiles -> grid 16x32=512
  gemm_bf16<2, 4><<<512, 512, 0, stream>>>(
      x_bf, wff1_t, FF, DM, 32, hbuf, nullptr, b_ff1, nullptr, nullptr);

  // FF2 + bias + residuals -> f32 out: 4096x2048 (K=8192), 256x128 -> grid 256
  gemm_bf16<3, 2><<<256, 256, 0, stream>>>(
      hbuf, wff2_t, DM, FF, 16, nullptr, out, b_ff2, x, attn_proj);
}

// Round 8
// 655.809 us; speedup vs baseline: 1.4031x; 1.0216x over previous
//
#include <hip/hip_runtime.h>
#include <hip/hip_bf16.h>
#include <cmath>

typedef __bf16 bf16x8 __attribute__((ext_vector_type(8)));
typedef float f32x4 __attribute__((ext_vector_type(4)));
typedef unsigned short u16;
typedef unsigned int u32;

#define DEV __device__ __forceinline__

static constexpr int BB = 2;
static constexpr int T = 2048;
static constexpr int DM = 2048;
static constexpr int NH = 16;
static constexpr int HD = 128;
static constexpr int FF = 8192;
static constexpr int M = BB * T;      // 4096
static constexpr int NQKV = 3 * DM;   // 6144

DEV u16 f2b(float f) {
  u32 u = __builtin_bit_cast(u32, f);
  u = (u + 0x7FFFu + ((u >> 16) & 1u)) >> 16;
  return (u16)u;
}
DEV float b2f(u16 h) {
  u32 u = ((u32)h) << 16;
  return __builtin_bit_cast(float, u);
}

// async global->LDS, 16B per lane; LDS dest = wave-uniform base + lane*16
DEV void gload16(const u16* g, const u16* l) {
  __builtin_amdgcn_global_load_lds(
      (const __attribute__((address_space(1))) void*)(uintptr_t)g,
      (__attribute__((address_space(3))) void*)(unsigned)(uintptr_t)l,
      16, 0, 0);
}

// ---------------- conversions ----------------

__global__ void cvt_f32_to_bf16(const float* __restrict__ in, u16* __restrict__ out, int n4) {
  int i = blockIdx.x * blockDim.x + threadIdx.x;
  if (i >= n4) return;
  float4 v = reinterpret_cast<const float4*>(in)[i];
  ushort4 o;
  o.x = f2b(v.x); o.y = f2b(v.y); o.z = f2b(v.z); o.w = f2b(v.w);
  reinterpret_cast<ushort4*>(out)[i] = o;
}

// W [K][N] f32  ->  Wt [N][K] bf16
__global__ void transpose_cvt(const float* __restrict__ W, u16* __restrict__ Wt, int K, int N) {
  __shared__ float tile[32][33];
  int nb = blockIdx.x * 32, kb = blockIdx.y * 32;
  int tx = threadIdx.x & 31, ty = threadIdx.x >> 5;  // ty 0..7
#pragma unroll
  for (int r = 0; r < 32; r += 8)
    tile[ty + r][tx] = W[(size_t)(kb + ty + r) * N + nb + tx];
  __syncthreads();
#pragma unroll
  for (int r = 0; r < 32; r += 8)
    Wt[(size_t)(nb + ty + r) * K + kb + tx] = f2b(tile[tx][ty + r]);
}

// ---------------- 8-phase GEMM (256x256, BK=64) ----------------
// C[M][N] = A[M][K]*Bt[N][K]^T. 8 waves as 2M x 4N, wave tile 128x64,
// acc 8x4 frags. 4 phases per K-tile, snake quadrant order
// p0(q00: A0xB0) p1(q01: A0xB1) p2(q11: A1xB1) p3(q10: A1xB0) so A-half and
// B-half frags stay register-resident (24 ds_read_b128 / K-tile / wave).
// LDS 128 KB: buf[2] x { A[256][64] | B[256][64] } bf16. Per phase stage ONE
// half-tile (2 gload16/thread) into a region whose last ds_read was >=1
// phase-barrier ago:
//   p0 -> alt.Ah1(kt+1)  [alt.Ah1 last read prev iter p2]
//   p1 -> alt.Bh1(kt+1)  [prev iter p1]
//   p2 -> cur.Ah0(kt+2)  [this iter p0]
//   p3 -> cur.Bh0(kt+2)  [this iter p0]
// Boundary wait once per K-tile: vmcnt(4) leaves p2/p3's 4 loads in flight,
// guarantees (FIFO) everything older landed => next K-tile fully staged.
// Chunk swizzle: LDS cell(row,c) holds global k-chunk c ^ (row&7); staged via
// pre-swizzled per-lane SOURCE (linear LDS dest), read at chunk q^(lr&7) --
// per-lane constant. 16 lanes/frag span all 8 chunk columns twice = 2/bank.
// s_setprio(1) around each MFMA cluster (T5; 8-phase prerequisite met).
template <int EPI>
__global__ __launch_bounds__(512, 2) void gemm8(
    const u16* __restrict__ A, const u16* __restrict__ Bt, int Ndim, int K, int gx,
    u16* __restrict__ out_bf, const float* __restrict__ bias) {
  __shared__ __align__(16) u16 lds[2 * 32768];  // 128 KB
  const int t = threadIdx.x;
  const int nwg = gridDim.x, cpx = nwg >> 3;
  const int wg = (blockIdx.x & 7) * cpx + (blockIdx.x >> 3);
  const int m0 = (wg / gx) * 256, n0 = (wg % gx) * 256;
  const int wave = t >> 6, lane = t & 63;
  const int wm = wave >> 2, wn = wave & 3;
  const int lr = lane & 15, lk = lane >> 4;

  // staging geometry: thread t covers row srow(+64,128,192), chunk t&7;
  // source chunk pre-swizzled by srow&7
  const int srow = t >> 3;
  const int sc8 = ((t & 7) ^ (srow & 7)) * 8;
  const u16* gA = &A[(size_t)(m0 + srow) * K + sc8];
  const u16* gB = &Bt[(size_t)(n0 + srow) * K + sc8];
  const int wls = wave * 512;  // wave chunk of a 4096-elem gload region

  u16* buf0 = lds;
  u16* buf1 = lds + 32768;

#define STAGE_A(buf, h, kt)                                                      \
  {                                                                              \
    gload16(gA + (size_t)((h) * 128) * K + (kt) * 64, (buf) + (h) * 8192 + wls); \
    gload16(gA + (size_t)((h) * 128 + 64) * K + (kt) * 64,                       \
            (buf) + (h) * 8192 + 4096 + wls);                                    \
  }
#define STAGE_B(buf, h, kt)                                                      \
  {                                                                              \
    gload16(gB + (size_t)((h) * 128) * K + (kt) * 64,                            \
            (buf) + 16384 + (h) * 8192 + wls);                                   \
    gload16(gB + (size_t)((h) * 128 + 64) * K + (kt) * 64,                       \
            (buf) + 16384 + (h) * 8192 + 4096 + wls);                            \
  }
#define PH_PRE                          \
  __builtin_amdgcn_sched_barrier(0);    \
  __builtin_amdgcn_s_barrier();         \
  __builtin_amdgcn_sched_barrier(0);    \
  __builtin_amdgcn_s_setprio(1);
#define PH_POST                         \
  __builtin_amdgcn_s_setprio(0);        \
  __builtin_amdgcn_sched_barrier(0);    \
  __builtin_amdgcn_s_barrier();         \
  __builtin_amdgcn_sched_barrier(0);

  const int NT = K >> 6;

  // prologue: K-tile 0 complete (8 loads) + K-tile 1 halves 0 (4 loads)
  STAGE_A(buf0, 0, 0); STAGE_A(buf0, 1, 0);
  STAGE_B(buf0, 0, 0); STAGE_B(buf0, 1, 0);
  STAGE_A(buf1, 0, 1); STAGE_B(buf1, 0, 1);
  __builtin_amdgcn_sched_barrier(0);
  asm volatile("s_waitcnt vmcnt(4)" ::: "memory");
  __builtin_amdgcn_s_barrier();
  __builtin_amdgcn_sched_barrier(0);

  f32x4 acc[8][4] = {};
  const int aBase = (wm * 128 + lr) * 64;
  const int bBase = 16384 + (wn * 64 + lr) * 64;
  const int c0 = (lk ^ (lr & 7)) * 8;
  const int c1 = ((4 + lk) ^ (lr & 7)) * 8;

  u16* cur = buf0;
  u16* alt = buf1;
  bf16x8 af[4][2], bq0[2][2], bq1[2][2];

  for (int kt = 0; kt < NT; ++kt) {
    // ---- p0: read A rows 0-3 + B cols 0-1; MFMA q(0,0); stage alt.Ah1(kt+1)
#pragma unroll
    for (int i = 0; i < 4; ++i) {
      af[i][0] = *(const bf16x8*)&cur[aBase + i * 1024 + c0];
      af[i][1] = *(const bf16x8*)&cur[aBase + i * 1024 + c1];
    }
#pragma unroll
    for (int j = 0; j < 2; ++j) {
      bq0[j][0] = *(const bf16x8*)&cur[bBase + j * 1024 + c0];
      bq0[j][1] = *(const bf16x8*)&cur[bBase + j * 1024 + c1];
    }
    if (kt + 1 < NT) STAGE_A(alt, 1, kt + 1);
    PH_PRE;
#pragma unroll
    for (int i = 0; i < 4; ++i)
#pragma unroll
      for (int j = 0; j < 2; ++j)
#pragma unroll
        for (int kk = 0; kk < 2; ++kk)
          acc[i][j] = __builtin_amdgcn_mfma_f32_16x16x32_bf16(af[i][kk], bq0[j][kk], acc[i][j], 0, 0, 0);
    PH_POST;
    // ---- p1: read B cols 2-3; MFMA q(0,1); stage alt.Bh1(kt+1)
#pragma unroll
    for (int j = 0; j < 2; ++j) {
      bq1[j][0] = *(const bf16x8*)&cur[bBase + (2 + j) * 1024 + c0];
      bq1[j][1] = *(const bf16x8*)&cur[bBase + (2 + j) * 1024 + c1];
    }
    if (kt + 1 < NT) STAGE_B(alt, 1, kt + 1);
    PH_PRE;
#pragma unroll
    for (int i = 0; i < 4; ++i)
#pragma unroll
      for (int j = 0; j < 2; ++j)
#pragma unroll
        for (int kk = 0; kk < 2; ++kk)
          acc[i][2 + j] = __builtin_amdgcn_mfma_f32_16x16x32_bf16(af[i][kk], bq1[j][kk], acc[i][2 + j], 0, 0, 0);
    PH_POST;
    // ---- p2: read A rows 4-7; MFMA q(1,1); stage cur.Ah0(kt+2)
#pragma unroll
    for (int i = 0; i < 4; ++i) {
      af[i][0] = *(const bf16x8*)&cur[aBase + (4 + i) * 1024 + c0];
      af[i][1] = *(const bf16x8*)&cur[aBase + (4 + i) * 1024 + c1];
    }
    if (kt + 2 < NT) STAGE_A(cur, 0, kt + 2);
    PH_PRE;
#pragma unroll
    for (int i = 0; i < 4; ++i)
#pragma unroll
      for (int j = 0; j < 2; ++j)
#pragma unroll
        for (int kk = 0; kk < 2; ++kk)
          acc[4 + i][2 + j] = __builtin_amdgcn_mfma_f32_16x16x32_bf16(af[i][kk], bq1[j][kk], acc[4 + i][2 + j], 0, 0, 0);
    PH_POST;
    // ---- p3: MFMA q(1,0) (regs only); stage cur.Bh0(kt+2); boundary vmcnt
    if (kt + 2 < NT) STAGE_B(cur, 0, kt + 2);
    PH_PRE;
#pragma unroll
    for (int i = 0; i < 4; ++i)
#pragma unroll
      for (int j = 0; j < 2; ++j)
#pragma unroll
        for (int kk = 0; kk < 2; ++kk)
          acc[4 + i][j] = __builtin_amdgcn_mfma_f32_16x16x32_bf16(af[i][kk], bq0[j][kk], acc[4 + i][j], 0, 0, 0);
    __builtin_amdgcn_s_setprio(0);
    __builtin_amdgcn_sched_barrier(0);
    if (kt + 2 < NT)      asm volatile("s_waitcnt vmcnt(4)" ::: "memory");
    else if (kt + 1 < NT) asm volatile("s_waitcnt vmcnt(0)" ::: "memory");
    __builtin_amdgcn_s_barrier();
    __builtin_amdgcn_sched_barrier(0);
    u16* tmp = cur; cur = alt; alt = tmp;
  }
#undef STAGE_A
#undef STAGE_B
#undef PH_PRE
#undef PH_POST

#pragma unroll
  for (int i = 0; i < 8; ++i) {
#pragma unroll
    for (int j = 0; j < 4; ++j) {
#pragma unroll
      for (int r = 0; r < 4; ++r) {
        int gr = m0 + wm * 128 + i * 16 + (lane >> 4) * 4 + r;
        int gc = n0 + wn * 64 + j * 16 + (lane & 15);
        float v = acc[i][j][r];
        if constexpr (EPI == 0) {  // qk scatter
          int part = gc >> 11, cc = gc & 2047;
          int head = cc >> 7, d = cc & 127;
          int b = gr >> 11, tt = gr & 2047;
          out_bf[(size_t)part * M * DM + (((size_t)(b * NH + head) * T + tt) * HD + d)] = f2b(v);
        } else {  // EPI 2: bias + tanh-GELU
          v += bias[gc];
          float u = v * (v * v * 0.044715f + 1.0f) * 0.7978845608028654f;
          float e = exp2f(u * 2.885390081777927f);
          float th = 1.0f - 2.0f / (e + 1.0f);
          v = 0.5f * v * (1.0f + th);
          out_bf[(size_t)gr * Ndim + gc] = f2b(v);
        }
      }
    }
  }
}

// ---------------- GEMM (round-6 engine: 256x128, 8 waves 64x64) ----------------
// 3-buffer LDS pipeline, counted vmcnt(3), raw s_barrier, chunk swizzle,
// XCD-bijective block swizzle. Proven config for the N=2048-class GEMMs.
// EPI 1: plain bf16; EPI 3: bias+residuals f32; EPI 4: V^T scatter
template <int EPI>
__global__ __launch_bounds__(512, 4) void gemm_bf16(
    const u16* __restrict__ A, const u16* __restrict__ Bt, int Ndim, int K, int gx,
    u16* __restrict__ out_bf, float* __restrict__ out_f32,
    const float* __restrict__ bias,
    const float* __restrict__ resid_f32, const u16* __restrict__ resid_bf) {
  __shared__ __align__(16) u16 lds[3 * (256 + 128) * 32];  // 72 KB
  const int t = threadIdx.x;
  const int nwg = gridDim.x, cpx = nwg >> 3;
  const int wg = (blockIdx.x & 7) * cpx + (blockIdx.x >> 3);
  const int m0 = (wg / gx) * 256, n0 = (wg % gx) * 128;
  const int wave = t >> 6, lane = t & 63;
  const int wm = wave >> 1, wn = wave & 1;  // 4 x 2 wave grid, 64x64 each
  const int lr = lane & 15, lk = lane >> 4;

  u16* cA = lds;                   u16* cB = lds + 8192;
  u16* nA = lds + 12288;           u16* nB = lds + 12288 + 8192;
  u16* sA = lds + 2 * 12288;       u16* sB = lds + 2 * 12288 + 8192;

  const int sk = ((lane & 3) ^ ((lane >> 3) & 3)) * 8;
  const u16* gA0 = &A[(size_t)(m0 + wave * 16 + (lane >> 2)) * K + sk];
  const u16* gA1 = gA0 + (size_t)128 * K;
  const u16* gB0 = &Bt[(size_t)(n0 + wave * 16 + (lane >> 2)) * K + sk];

  const int wbase = wave * 512;

  auto stage = [&](u16* dA, u16* dB) {
    gload16(gA0, dA + wbase);
    gload16(gA1, dA + 4096 + wbase);
    gload16(gB0, dB + wbase);
    gA0 += 32; gA1 += 32; gB0 += 32;
  };

  const int NT = K >> 5;

  stage(cA, cB);
  stage(nA, nB);
  __builtin_amdgcn_sched_barrier(0);
  asm volatile("s_waitcnt vmcnt(3)" ::: "memory");
  __builtin_amdgcn_s_barrier();
  __builtin_amdgcn_sched_barrier(0);

  f32x4 acc[4][4] = {};
  const int rcol = (lk ^ ((lr >> 1) & 3)) * 8;

  for (int kt = 0; kt < NT; ++kt) {
    if (kt + 2 < NT) stage(sA, sB);
    bf16x8 af[4], bfr[4];
#pragma unroll
    for (int i = 0; i < 4; ++i) {
      af[i]  = *reinterpret_cast<const bf16x8*>(&cA[(wm * 64 + i * 16 + lr) * 32 + rcol]);
      bfr[i] = *reinterpret_cast<const bf16x8*>(&cB[(wn * 64 + i * 16 + lr) * 32 + rcol]);
    }
#pragma unroll
    for (int i = 0; i < 4; ++i)
#pragma unroll
      for (int j = 0; j < 4; ++j)
        acc[i][j] = __builtin_amdgcn_mfma_f32_16x16x32_bf16(af[i], bfr[j], acc[i][j], 0, 0, 0);
    if (kt + 1 < NT) {
      __builtin_amdgcn_sched_barrier(0);
      if (kt + 2 < NT) asm volatile("s_waitcnt vmcnt(3)" ::: "memory");
      else             asm volatile("s_waitcnt vmcnt(0)" ::: "memory");
      __builtin_amdgcn_s_barrier();
      __builtin_amdgcn_sched_barrier(0);
      u16* tA = cA; u16* tB = cB;
      cA = nA; cB = nB; nA = sA; nB = sB; sA = tA; sB = tB;
    }
  }

#pragma unroll
  for (int i = 0; i < 4; ++i) {
#pragma unroll
    for (int j = 0; j < 4; ++j) {
#pragma unroll
      for (int r = 0; r < 4; ++r) {
        int gr = m0 + wm * 64 + i * 16 + (lane >> 4) * 4 + r;
        int gc = n0 + wn * 64 + j * 16 + (lane & 15);
        float v = acc[i][j][r];
        if constexpr (EPI == 1) {
          out_bf[(size_t)gr * Ndim + gc] = f2b(v);
        } else if constexpr (EPI == 3) {
          v += bias[gc] + resid_f32[(size_t)gr * Ndim + gc] + b2f(resid_bf[(size_t)gr * Ndim + gc]);
          out_f32[(size_t)gr * Ndim + gc] = v;
        } else {  // EPI 4: V^T
          int hh = gr >> 7, d = gr & 127;
          int b = gc >> 11, tt = gc & 2047;
          out_bf[((size_t)(b * NH + hh) * HD + d) * T + tt] = f2b(v);
        }
      }
    }
  }
}

// ---------------- attention ----------------
// grid (T/64, B*NH); 4 waves, each owns 16 q-rows; KV tiles of 64; causal flash.
// Longest-first dispatch; defer-max rescale (T13, log2 THR=11.5).
__global__ __launch_bounds__(256) void attn_fwd(
    const u16* __restrict__ qg, const u16* __restrict__ kg,
    const u16* __restrict__ vt, u16* __restrict__ outg) {
  __shared__ __align__(16) u16 lK[64 * 128];    // 16 KB
  __shared__ __align__(16) u16 lVt[128 * 64];   // 16 KB
  __shared__ __align__(16) u16 lP[4][16 * 72];
  const int t = threadIdx.x;
  const int qi = gridDim.x - 1 - blockIdx.x;   // longest blocks first
  const int bh = blockIdx.y;
  const int wv = t >> 6, lane = t & 63;
  const int lc = lane & 15, lg = lane >> 4;
  const size_t base = (size_t)bh * T * HD;   // q, k: [T][HD]
  const size_t vbase = (size_t)bh * HD * T;  // vt:   [HD][T]
  const int q0 = qi * 64;

  bf16x8 qf[4];
#pragma unroll
  for (int kk = 0; kk < 4; ++kk)
    qf[kk] = *reinterpret_cast<const bf16x8*>(
        &qg[base + (size_t)(q0 + wv * 16 + lc) * HD + kk * 32 + lg * 8]);

  f32x4 oacc[8] = {};
  float mrow[4], lrow[4];
#pragma unroll
  for (int r = 0; r < 4; ++r) { mrow[r] = -INFINITY; lrow[r] = 0.f; }

  const float scaleL = 0.08838834764831845f * 1.4426950408889634f;
  const int ntiles = qi + 1;
  for (int kt = 0; kt < ntiles; ++kt) {
    __syncthreads();
#pragma unroll
    for (int h = 0; h < 4; ++h) {
      int row = h * 16 + wv * 4 + (lane >> 4);
      int sb = ((lane & 15) * 16) ^ ((row & 7) << 4);
      gload16(&kg[base + (size_t)(kt * 64 + row) * HD + (sb >> 1)],
              (const u16*)((const char*)lK + (h * 256 + wv * 64) * 16));
    }
#pragma unroll
    for (int h = 0; h < 4; ++h) {
      int row = h * 32 + wv * 8 + (lane >> 3);
      int sb = ((lane & 7) * 16) ^ ((row & 7) << 4);
      gload16(&vt[vbase + (size_t)row * T + kt * 64 + (sb >> 1)],
              (const u16*)((const char*)lVt + (h * 256 + wv * 64) * 16));
    }
    __syncthreads();

    f32x4 s[4] = {};
#pragma unroll
    for (int nf = 0; nf < 4; ++nf) {
      int krow = nf * 16 + lc;
#pragma unroll
      for (int kk = 0; kk < 4; ++kk) {
        int dbyte = kk * 64 + lg * 16;
        bf16x8 kf = *reinterpret_cast<const bf16x8*>(
            reinterpret_cast<const char*>(lK) + krow * 256 + (dbyte ^ ((krow & 7) << 4)));
        s[nf] = __builtin_amdgcn_mfma_f32_16x16x32_bf16(qf[kk], kf, s[nf], 0, 0, 0);
      }
    }

    float rmax[4];
#pragma unroll
    for (int r = 0; r < 4; ++r) rmax[r] = -INFINITY;
#pragma unroll
    for (int nf = 0; nf < 4; ++nf) {
      int col = kt * 64 + nf * 16 + lc;
#pragma unroll
      for (int r = 0; r < 4; ++r) {
        int row = q0 + wv * 16 + lg * 4 + r;
        float sv = s[nf][r] * scaleL;
        if (col > row) sv = -INFINITY;
        s[nf][r] = sv;
        rmax[r] = fmaxf(rmax[r], sv);
      }
    }
#pragma unroll
    for (int mk = 1; mk < 16; mk <<= 1)
#pragma unroll
      for (int r = 0; r < 4; ++r)
        rmax[r] = fmaxf(rmax[r], __shfl_xor(rmax[r], mk));

    int need = 0;
#pragma unroll
    for (int r = 0; r < 4; ++r) need |= (rmax[r] > mrow[r] + 11.5f) ? 1 : 0;
    if (__any(need)) {
      float corr[4];
#pragma unroll
      for (int r = 0; r < 4; ++r) {
        float mnew = fmaxf(mrow[r], rmax[r]);
        corr[r] = exp2f(mrow[r] - mnew);
        mrow[r] = mnew;
        lrow[r] *= corr[r];
      }
#pragma unroll
      for (int dc = 0; dc < 8; ++dc)
#pragma unroll
        for (int r = 0; r < 4; ++r) oacc[dc][r] *= corr[r];
    }

#pragma unroll
    for (int nf = 0; nf < 4; ++nf) {
#pragma unroll
      for (int r = 0; r < 4; ++r) {
        float p = exp2f(s[nf][r] - mrow[r]);
        lrow[r] += p;
        lP[wv][(lg * 4 + r) * 72 + nf * 16 + lc] = f2b(p);
      }
    }
    bf16x8 pa[2];
#pragma unroll
    for (int kk = 0; kk < 2; ++kk)
      pa[kk] = *reinterpret_cast<const bf16x8*>(&lP[wv][lc * 72 + kk * 32 + lg * 8]);
#pragma unroll
    for (int dc = 0; dc < 8; ++dc) {
#pragma unroll
      for (int kk = 0; kk < 2; ++kk) {
        int vrow = dc * 16 + lc;
        int off = (kk * 64 + lg * 16) ^ ((vrow & 7) << 4);
        bf16x8 vf = *reinterpret_cast<const bf16x8*>(
            reinterpret_cast<const char*>(lVt) + vrow * 128 + off);
        oacc[dc] = __builtin_amdgcn_mfma_f32_16x16x32_bf16(pa[kk], vf, oacc[dc], 0, 0, 0);
      }
    }
  }

#pragma unroll
  for (int mk = 1; mk < 16; mk <<= 1)
#pragma unroll
    for (int r = 0; r < 4; ++r) lrow[r] += __shfl_xor(lrow[r], mk);

  const int b = bh >> 4, hh = bh & 15;
#pragma unroll
  for (int dc = 0; dc < 8; ++dc)
#pragma unroll
    for (int r = 0; r < 4; ++r) {
      int tt = q0 + wv * 16 + lg * 4 + r;
      int d = dc * 16 + lc;
      float o = oacc[dc][r] / lrow[r];
      outg[(size_t)(b * T + tt) * DM + hh * HD + d] = f2b(o);
    }
}

// ---------------- launch ----------------

extern "C" void kernel_launch(void* const* d_in, const int* in_sizes, int n_in,
                              void* d_out, int out_size, void* d_ws, size_t ws_size,
                              hipStream_t stream) {
  const float* x      = (const float*)d_in[0];
  const float* w_qkv  = (const float*)d_in[1];
  const float* w_proj = (const float*)d_in[2];
  const float* w_ff1  = (const float*)d_in[3];
  const float* b_ff1  = (const float*)d_in[4];
  const float* w_ff2  = (const float*)d_in[5];
  const float* b_ff2  = (const float*)d_in[6];
  float* out = (float*)d_out;

  u16* ws = (u16*)d_ws;
  size_t o = 0;
  u16* x_bf      = ws + o; o += (size_t)M * DM;
  u16* wqkv_t    = ws + o; o += (size_t)NQKV * DM;
  u16* wproj_t   = ws + o; o += (size_t)DM * DM;
  u16* wff1_t    = ws + o; o += (size_t)FF * DM;
  u16* wff2_t    = ws + o; o += (size_t)DM * FF;
  u16* attn_proj = ws + o; o += (size_t)M * DM;
  u16* qbuf      = ws + o;                    // q,k,vt,attn_out contiguous
  u16* kbuf      = qbuf + (size_t)M * DM;
  u16* vtbuf     = kbuf + (size_t)M * DM;     // V^T: [B][H][HD][T]
  u16* attn_out  = vtbuf + (size_t)M * DM;
  u16* hbuf      = qbuf;                      // aliases q|k|vt|attn_out = M*FF elems

  // conversions
  cvt_f32_to_bf16<<<(M * DM / 4 + 255) / 256, 256, 0, stream>>>(x, x_bf, M * DM / 4);
  transpose_cvt<<<dim3(NQKV / 32, DM / 32), 256, 0, stream>>>(w_qkv, wqkv_t, DM, NQKV);
  transpose_cvt<<<dim3(DM / 32, DM / 32), 256, 0, stream>>>(w_proj, wproj_t, DM, DM);
  transpose_cvt<<<dim3(FF / 32, DM / 32), 256, 0, stream>>>(w_ff1, wff1_t, DM, FF);
  transpose_cvt<<<dim3(DM / 32, FF / 32), 256, 0, stream>>>(w_ff2, wff2_t, FF, DM);

  // q,k projection (scatter): 4096x4096, 256x256 -> grid 256
  gemm8<0><<<256, 512, 0, stream>>>(x_bf, wqkv_t, 4096, DM, 16, qbuf, nullptr);

  // V^T = Wv^T X^T: 2048x4096, 256x128 -> grid 8x32=256
  gemm_bf16<4><<<256, 512, 0, stream>>>(
      wqkv_t + (size_t)4096 * DM, x_bf, M, DM, 32, vtbuf, nullptr, nullptr, nullptr, nullptr);

  // causal flash attention
  attn_fwd<<<dim3(T / 64, BB * NH), 256, 0, stream>>>(qbuf, kbuf, vtbuf, attn_out);

  // output projection: 4096x2048, 256x128 -> grid 256
  gemm_bf16<1><<<256, 512, 0, stream>>>(
      attn_out, wproj_t, DM, DM, 16, attn_proj, nullptr, nullptr, nullptr, nullptr);

  // FF1 + GELU: 4096x8192, 256x256 -> grid 16x32=512
  gemm8<2><<<512, 512, 0, stream>>>(x_bf, wff1_t, FF, DM, 32, hbuf, b_ff1);

  // FF2 + bias + residuals -> f32 out: 4096x2048 (K=8192), 256x128 -> grid 256
  gemm_bf16<3><<<256, 512, 0, stream>>>(
      hbuf, wff2_t, DM, FF, 16, nullptr, out, b_ff2, x, attn_proj);
}